// Round 15
// baseline (482.013 us; speedup 1.0000x reference)
//
#include <hip/hip_runtime.h>

typedef unsigned int u32;
typedef unsigned long long u64;
typedef unsigned short u16;

typedef __attribute__((ext_vector_type(8))) short bf16x8;
typedef __attribute__((ext_vector_type(4))) float f32x4;

#define FEAT 256
#define MEMN 100000

// Prevent fp contraction (hipcc defaults -ffp-contract=fast).
#define OPAQ(x) asm volatile("" : "+v"(x))

static __device__ __forceinline__ u16 f2bf(float x){   // round-to-nearest-even
  u32 u = __float_as_uint(x);
  u32 r = u + 0x7fffu + ((u >> 16) & 1u);
  return (u16)(r >> 16);
}

// ---------------- f32 GEMM, OpenBLAS-replica bits; 32x64 tile, 2x4/thread, 256 thr -----
// Per-element arithmetic FROZEN (k-ascending FMA chain, kc=384 panel flushes).
// r14 lesson: 64x64 tile -> 1 block/CU -> 1 wave/SIMD -> latency-exposed (VALU 34%).
// BM=32 doubles the grid: G1 = 512 blocks = 2 blocks/CU = 2 waves/SIMD.
template<int RELU>
__global__ __launch_bounds__(256) void gemm_seq_k(const float* __restrict__ A,
                                                  const float* __restrict__ Bm,
                                                  const float* __restrict__ bias,
                                                  float* __restrict__ C,
                                                  int M, int N, int K){
  __shared__ float At[2][32][36];   // [buf][k][row], 36 = 32 + pad (16B-aligned rows)
  __shared__ float Bs[2][32][68];   // [buf][k][col]
  const int t = threadIdx.x;
  const int tx = t & 15, ty = t >> 4;          // col-quad 0..15, row-pair 0..15
  const int bm = blockIdx.y << 5, bn = blockIdx.x << 6;
  float acc[2][4], mast[2][4];
  #pragma unroll
  for (int i = 0; i < 2; i++)
    #pragma unroll
    for (int j = 0; j < 4; j++){ acc[i][j] = 0.f; mast[i][j] = 0.f; }

  float pa[4], pb[8];
  #pragma unroll
  for (int i = 0; i < 4; i++){
    int o = t + (i << 8);                      // 0..1023 (A: 32 rows x 32 k)
    pa[i] = A[(u64)(bm + (o >> 5)) * K + (o & 31)];
  }
  #pragma unroll
  for (int i = 0; i < 8; i++){
    int o = t + (i << 8);                      // 0..2047 (B: 32 k x 64 cols)
    pb[i] = Bm[(u64)(o >> 6) * N + bn + (o & 63)];
  }
  #pragma unroll
  for (int i = 0; i < 4; i++){ int o = t + (i << 8); At[0][o & 31][o >> 5] = pa[i]; }
  #pragma unroll
  for (int i = 0; i < 8; i++){ int o = t + (i << 8); Bs[0][o >> 6][o & 63] = pb[i]; }
  __syncthreads();

  int cur = 0;
  for (int kt = 0; kt < K; kt += 32){
    const int nxt = kt + 32;
    if (nxt < K){
      #pragma unroll
      for (int i = 0; i < 4; i++){
        int o = t + (i << 8);
        pa[i] = A[(u64)(bm + (o >> 5)) * K + nxt + (o & 31)];
      }
      #pragma unroll
      for (int i = 0; i < 8; i++){
        int o = t + (i << 8);
        pb[i] = Bm[(u64)(nxt + (o >> 6)) * N + bn + (o & 63)];
      }
    }
    #pragma unroll
    for (int k = 0; k < 32; k++){    // ascending k: frozen chain
      float2 av = *reinterpret_cast<const float2*>(&At[cur][k][ty << 1]);
      float4 bv = *reinterpret_cast<const float4*>(&Bs[cur][k][tx << 2]);
      acc[0][0] = fmaf(av.x, bv.x, acc[0][0]); acc[0][1] = fmaf(av.x, bv.y, acc[0][1]);
      acc[0][2] = fmaf(av.x, bv.z, acc[0][2]); acc[0][3] = fmaf(av.x, bv.w, acc[0][3]);
      acc[1][0] = fmaf(av.y, bv.x, acc[1][0]); acc[1][1] = fmaf(av.y, bv.y, acc[1][1]);
      acc[1][2] = fmaf(av.y, bv.z, acc[1][2]); acc[1][3] = fmaf(av.y, bv.w, acc[1][3]);
    }
    if ((nxt % 384) == 0 || nxt == K){   // OpenBLAS kc=384 panel flush (frozen)
      #pragma unroll
      for (int i = 0; i < 2; i++)
        #pragma unroll
        for (int j = 0; j < 4; j++){ mast[i][j] = mast[i][j] + acc[i][j]; acc[i][j] = 0.f; }
    }
    if (nxt < K){
      #pragma unroll
      for (int i = 0; i < 4; i++){ int o = t + (i << 8); At[cur ^ 1][o & 31][o >> 5] = pa[i]; }
      #pragma unroll
      for (int i = 0; i < 8; i++){ int o = t + (i << 8); Bs[cur ^ 1][o >> 6][o & 63] = pb[i]; }
      __syncthreads();
      cur ^= 1;
    }
  }
  #pragma unroll
  for (int i = 0; i < 2; i++){
    int row = bm + (ty << 1) + i;
    #pragma unroll
    for (int j = 0; j < 4; j++){
      int col = bn + (tx << 2) + j;
      float v = mast[i][j] + bias[col];
      if (RELU) v = v > 0.f ? v : 0.f;
      C[(u64)row * N + col] = v;
    }
  }
}

// ---------------- f_sum: sequential f32 over rows (frozen chains; 4 blocks) ------------
__global__ __launch_bounds__(64) void fsum_seq_k(const float* __restrict__ f,
                                                 float* __restrict__ fsum){
  int d = (blockIdx.x << 6) + threadIdx.x;
  float s = 0.f;
  for (int r = 0; r < 2048; r++) s += f[(u64)r * FEAT + d];
  fsum[d] = s;
}

// ==== numpy npyv-AVX512 pairwise base case for one 128-block of SQUARES (frozen) =======
__device__ __forceinline__ float block128_sq_avx512(const float4* base, int off, int swz){
  float e0[16], e1[16], f0[16], s16[16];
  #pragma unroll
  for (int j = 0; j < 8; j++){
    #pragma unroll
    for (int q = 0; q < 4; q++){
      float4 v = base[off + (((j << 2) + q) ^ swz)];
      float p0 = v.x * v.x, p1 = v.y * v.y, p2 = v.z * v.z, p3 = v.w * v.w;
      OPAQ(p0); OPAQ(p1); OPAQ(p2); OPAQ(p3);
      int l = q << 2;
      if (j == 0 || j == 4){ e0[l] = p0; e0[l+1] = p1; e0[l+2] = p2; e0[l+3] = p3; }
      else if (j == 1 || j == 5){ e0[l] += p0; e0[l+1] += p1; e0[l+2] += p2; e0[l+3] += p3; }
      else if (j == 2 || j == 6){ e1[l] = p0; e1[l+1] = p1; e1[l+2] = p2; e1[l+3] = p3; }
      else { e1[l] += p0; e1[l+1] += p1; e1[l+2] += p2; e1[l+3] += p3; }
    }
    if (j == 3){
      #pragma unroll
      for (int l = 0; l < 16; l++) f0[l] = e0[l] + e1[l];
    }
    if (j == 7){
      #pragma unroll
      for (int l = 0; l < 16; l++) s16[l] = f0[l] + (e0[l] + e1[l]);
    }
  }
  float h8[8], h4[4], h2[2];
  #pragma unroll
  for (int l = 0; l < 8; l++) h8[l] = s16[l] + s16[l + 8];
  #pragma unroll
  for (int l = 0; l < 4; l++) h4[l] = h8[l] + h8[l + 4];
  h2[0] = h4[0] + h4[2]; h2[1] = h4[1] + h4[3];
  return h2[0] + h2[1];
}

// ---------------- f_sq leaves + combine (frozen) ---------------------------------------
__global__ __launch_bounds__(256) void leaf_k(const float* __restrict__ f,
                                              float* __restrict__ lf){
  int b = blockIdx.x * 256 + threadIdx.x;
  lf[b] = block128_sq_avx512((const float4*)(f + (u64)b * 128), 0, 0);
}

__global__ __launch_bounds__(1024) void tree_k(const float* __restrict__ lf,
                                               float* __restrict__ fsq){
  __shared__ float sa[4096];
  __shared__ float sb[2048];
  int t = threadIdx.x;
  for (int i = t; i < 4096; i += 1024) sa[i] = lf[i];
  __syncthreads();
  float* src = sa; float* dst = sb;
  for (int len = 2048; len >= 1; len >>= 1){
    for (int i = t; i < len; i += 1024) dst[i] = src[2 * i] + src[2 * i + 1];
    __syncthreads();
    float* tmp = src; src = dst; dst = tmp;
  }
  if (t == 0) *fsq = src[0];
}

// ---------------- per-row score: 2 threads/row + 16-wide register preload (r14, kept) --
__global__ __launch_bounds__(256) void score_row_k(const float* __restrict__ mem,
                                                   const float* __restrict__ fsum,
                                                   const float* __restrict__ fsq_p,
                                                   u32* __restrict__ keys,
                                                   u32* __restrict__ hist,
                                                   u32* __restrict__ hist2){
  __shared__ __align__(16) float fs[256];
  __shared__ u32 lh2[256];
  const int t = threadIdx.x;
  fs[t] = fsum[t];
  lh2[t] = 0;
  __syncthreads();
  const int sub = t & 1;
  const int row = (blockIdx.x << 7) + (t >> 1);
  float key_s = 0.f; bool live = (row < MEMN);
  if (live){
    const float4* rowp = (const float4*)(mem + (u64)row * FEAT);
    const float4* s4 = (const float4*)fs;
    float dpr[4];
    #pragma unroll
    for (int j = 0; j < 4; j++) dpr[j] = 0.f;
    float msqh[2];
    #pragma unroll
    for (int blk = 0; blk < 2; blk++){
      const int off = blk << 5;
      float4 mvv[16];                              // 16 independent loads, issued together
      #pragma unroll
      for (int j = 0; j < 8; j++)
        #pragma unroll
        for (int cs = 0; cs < 2; cs++)
          mvv[(j << 1) | cs] = rowp[off + (j << 2) + sub + (cs << 1)];
      float e0L[8], e1L[8], f0L[8], s16L[8];
      #pragma unroll
      for (int j = 0; j < 8; j++){
        #pragma unroll
        for (int cs = 0; cs < 2; cs++){
          int kb = off + (j << 2) + sub + (cs << 1);
          float4 v = mvv[(j << 1) | cs];
          float4 fv = s4[kb];
          float p0 = v.x * v.x, p1 = v.y * v.y, p2 = v.z * v.z, p3 = v.w * v.w;
          OPAQ(p0); OPAQ(p1); OPAQ(p2); OPAQ(p3);
          int li = cs << 2;
          if (j == 0 || j == 4){ e0L[li] = p0; e0L[li+1] = p1; e0L[li+2] = p2; e0L[li+3] = p3; }
          else if (j == 1 || j == 5){ e0L[li] += p0; e0L[li+1] += p1; e0L[li+2] += p2; e0L[li+3] += p3; }
          else if (j == 2 || j == 6){ e1L[li] = p0; e1L[li+1] = p1; e1L[li+2] = p2; e1L[li+3] = p3; }
          else { e1L[li] += p0; e1L[li+1] += p1; e1L[li+2] += p2; e1L[li+3] += p3; }
          dpr[0] = fmaf(v.x, fv.x, dpr[0]);
          dpr[1] = fmaf(v.y, fv.y, dpr[1]);
          dpr[2] = fmaf(v.z, fv.z, dpr[2]);
          dpr[3] = fmaf(v.w, fv.w, dpr[3]);
        }
        if (j == 3){
          #pragma unroll
          for (int l = 0; l < 8; l++) f0L[l] = e0L[l] + e1L[l];
        }
        if (j == 7){
          #pragma unroll
          for (int l = 0; l < 8; l++) s16L[l] = f0L[l] + (e0L[l] + e1L[l]);
        }
      }
      float h8L[4], oth[4], h4v[4];
      #pragma unroll
      for (int l = 0; l < 4; l++) h8L[l] = s16L[l] + s16L[4 + l];
      #pragma unroll
      for (int l = 0; l < 4; l++) oth[l] = __shfl_xor(h8L[l], 1);
      #pragma unroll
      for (int l = 0; l < 4; l++) h4v[l] = h8L[l] + oth[l];    // commutative: same bits
      float h2a = h4v[0] + h4v[2], h2b = h4v[1] + h4v[3];
      msqh[blk] = h2a + h2b;
    }
    float msq = msqh[0] + msqh[1];
    float od[4];
    #pragma unroll
    for (int i = 0; i < 4; i++) od[i] = __shfl_xor(dpr[i], 1);
    float b0 = dpr[0] + od[0], b1 = dpr[1] + od[1];
    float b2 = dpr[2] + od[2], b3 = dpr[3] + od[3];
    float dp = (b0 + b1) + (b2 + b3);
    float t1 = 2048.0f * msq;
    float t2 = 2.0f * dp;
    float d3 = t1 - t2;  OPAQ(d3);
    float d4 = d3 + fsq_p[0];
    key_s = -d4;
  }
  if (live && sub == 0){
    u32 bb = __float_as_uint(key_s);
    u32 key = (bb & 0x80000000u) ? ~bb : (bb | 0x80000000u);
    keys[row] = key;
    atomicAdd(&hist[key >> 14], 1u);
    atomicAdd(&lh2[key >> 24], 1u);
  }
  __syncthreads();
  u32 v = lh2[t];
  if (v) atomicAdd(&hist2[t], v);
}

// ---------------- threshold fine-bin: count(bins >= T) >= 2048 -------------------------
__global__ __launch_bounds__(1024) void find_T_k(const u32* __restrict__ hist,
                                                 const u32* __restrict__ hist2,
                                                 u32* __restrict__ Tbin){
  __shared__ u32 h2[256];
  __shared__ int sh_c;
  __shared__ u32 sh_run;
  __shared__ u32 sa[1024], sb[1024];
  int t = threadIdx.x;
  if (t < 256) h2[t] = hist2[t];
  __syncthreads();
  if (t == 0){
    u32 run = 0; int cstar = 0;
    for (int c = 255; c >= 0; c--){
      u32 v = h2[c];
      if (run + v >= 2048u){ cstar = c; break; }
      run += v;
    }
    sh_c = cstar; sh_run = run;
  }
  __syncthreads();
  int cstar = sh_c; u32 run = sh_run;
  sa[t] = hist[cstar * 1024 + t];
  __syncthreads();
  u32* src = sa; u32* dst = sb;
  for (int off = 1; off < 1024; off <<= 1){
    u32 v = src[t];
    if (t + off < 1024) v += src[t + off];
    dst[t] = v;
    __syncthreads();
    u32* tmp = src; src = dst; dst = tmp;
  }
  u32 suf  = src[t];
  u32 sufn = (t < 1023) ? src[t + 1] : 0u;
  if (run + suf >= 2048u && !(run + sufn >= 2048u)) *Tbin = (u32)(cstar * 1024 + t);
}

// ---------------- compact candidates into packed (key desc, idx asc) u64 ---------------
__global__ __launch_bounds__(256) void compact_k(const u32* __restrict__ keys,
                                                 const u32* __restrict__ Tbin,
                                                 u64* __restrict__ pk,
                                                 u32* __restrict__ counter){
  int i = blockIdx.x * 256 + threadIdx.x;
  if (i >= MEMN) return;
  u32 k = keys[i];
  if ((k >> 14) >= *Tbin){
    u32 p = atomicAdd(counter, 1u);
    if (p < 4096u) pk[p] = ((u64)k << 32) | (u32)(0xFFFFFFFFu - (u32)i);
  }
}

// ---------------- one-block bitonic sort of 4096 u64 desc ------------------------------
__global__ __launch_bounds__(1024) void sort_k(const u64* __restrict__ pkin,
                                               u32* __restrict__ idxo){
  __shared__ u64 k[4096];
  for (int i = threadIdx.x; i < 4096; i += 1024) k[i] = pkin[i];
  __syncthreads();
  for (int size = 2; size <= 4096; size <<= 1){
    for (int stride = size >> 1; stride; stride >>= 1){
      #pragma unroll 2
      for (int pp = 0; pp < 2; pp++){
        int p = threadIdx.x + pp * 1024;
        int i = ((p / stride) * (stride << 1)) + (p % stride);
        int j = i + stride;
        u64 a = k[i], b = k[j];
        bool desc_ok = (a >= b);
        bool up = ((i & size) == 0);
        if (up ? !desc_ok : desc_ok){ k[i] = b; k[j] = a; }
      }
      __syncthreads();
    }
  }
  for (int i = threadIdx.x; i < 2048; i += 1024) idxo[i] = 0xFFFFFFFFu - (u32)k[i];
}

// ---------------- h = concat(f, memory[idx]) -> bf16 -----------------------------------
__global__ __launch_bounds__(256) void build_h_k(const float* __restrict__ f,
                                                 const float* __restrict__ mem,
                                                 const u32* __restrict__ idx,
                                                 u16* __restrict__ h){
  int r = blockIdx.x, t = threadIdx.x;
  h[(u64)r * 512 + t] = f2bf(f[(u64)r * FEAT + t]);
  h[(u64)r * 512 + 256 + t] = f2bf(mem[(u64)idx[r] * FEAT + t]);
}

// ---------------- transpose-convert W[K,N] f32 -> WT[N,K] bf16 -------------------------
__global__ void convT_k(const float* __restrict__ W, u16* __restrict__ WT, int K, int N){
  __shared__ float tile[32][33];
  int tx = threadIdx.x, ty = threadIdx.y;  // blockDim (32,8)
  int bk = blockIdx.y << 5, bn = blockIdx.x << 5;
  #pragma unroll
  for (int i = 0; i < 4; i++){
    int r = ty + (i << 3);
    tile[r][tx] = W[(u64)(bk + r) * N + bn + tx];
  }
  __syncthreads();
  #pragma unroll
  for (int i = 0; i < 4; i++){
    int n = ty + (i << 3);
    WT[(u64)(bn + n) * K + bk + tx] = f2bf(tile[tx][n]);
  }
}

// ---------------- bf16 MFMA GEMM (m97 template): C = act(A @ BT^T + bias) --------------
static __device__ __forceinline__ void gl_lds16(const u16* g, u16* l){
  __builtin_amdgcn_global_load_lds((const __attribute__((address_space(1))) void*)g,
                                   (__attribute__((address_space(3))) void*)l, 16, 0, 0);
}

template<int RELU, int OUTBF>
__global__ __launch_bounds__(256) void gemm_bf16_k(const u16* __restrict__ A,
                                                   const u16* __restrict__ BT,
                                                   const float* __restrict__ bias,
                                                   void* __restrict__ Cout,
                                                   int M, int N, int K){
  __shared__ u16 As[128 * 32];
  __shared__ u16 Bs[128 * 32];
  const int t = threadIdx.x;
  const int w = t >> 6, lane = t & 63;
  const int bm = blockIdx.y << 7, bn = blockIdx.x << 7;
  f32x4 acc[4][4];
  #pragma unroll
  for (int i = 0; i < 4; i++)
    #pragma unroll
    for (int j = 0; j < 4; j++) acc[i][j] = (f32x4){0.f, 0.f, 0.f, 0.f};
  const int row0 = (w >> 1) << 6, col0 = (w & 1) << 6;
  for (int kt = 0; kt < K; kt += 32){
    #pragma unroll
    for (int j = 0; j < 2; j++){
      int e = (((j << 2) + w) << 9) + (lane << 3);
      int r = e >> 5, c = e & 31;
      gl_lds16(A  + (u64)(bm + r) * K + kt + c, As + (((j << 2) + w) << 9));
      gl_lds16(BT + (u64)(bn + r) * K + kt + c, Bs + (((j << 2) + w) << 9));
    }
    __syncthreads();
    bf16x8 af[4], bfr[4];
    #pragma unroll
    for (int i = 0; i < 4; i++){
      af[i]  = *(const bf16x8*)(As + (row0 + (i << 4) + (lane & 15)) * 32 + ((lane >> 4) << 3));
      bfr[i] = *(const bf16x8*)(Bs + (col0 + (i << 4) + (lane & 15)) * 32 + ((lane >> 4) << 3));
    }
    #pragma unroll
    for (int i = 0; i < 4; i++)
      #pragma unroll
      for (int j = 0; j < 4; j++)
        acc[i][j] = __builtin_amdgcn_mfma_f32_16x16x32_bf16(af[i], bfr[j], acc[i][j], 0, 0, 0);
    __syncthreads();
  }
  #pragma unroll
  for (int i = 0; i < 4; i++){
    #pragma unroll
    for (int j = 0; j < 4; j++){
      #pragma unroll
      for (int r = 0; r < 4; r++){
        int row = bm + row0 + (i << 4) + ((lane >> 4) << 2) + r;
        int col = bn + col0 + (j << 4) + (lane & 15);
        float v = acc[i][j][r] + bias[col];
        if (RELU) v = v > 0.f ? v : 0.f;
        if (OUTBF) ((u16*)Cout)[(u64)row * N + col] = f2bf(v);
        else       ((float*)Cout)[(u64)row * N + col] = v;
      }
    }
  }
}

// ======================================================================================
extern "C" void kernel_launch(void* const* d_in, const int* in_sizes, int n_in,
                              void* d_out, int out_size, void* d_ws, size_t ws_size,
                              hipStream_t stream){
  const float* x   = (const float*)d_in[0];
  const float* W1  = (const float*)d_in[1];
  const float* b1  = (const float*)d_in[2];
  const float* W2  = (const float*)d_in[3];
  const float* b2  = (const float*)d_in[4];
  const float* W3  = (const float*)d_in[5];
  const float* b3  = (const float*)d_in[6];
  const float* mem = (const float*)d_in[7];
  const float* Wt1 = (const float*)d_in[8];
  const float* bt1 = (const float*)d_in[9];
  const float* Wt2 = (const float*)d_in[10];
  const float* bt2 = (const float*)d_in[11];
  const float* Wo  = (const float*)d_in[12];
  const float* bo  = (const float*)d_in[13];

  char* ws = (char*)d_ws;
  float* f1   = (float*)(ws + 0);
  u32*   keys = (u32*)  (ws + 0);                        // 400 KB (dead-f1 reuse)
  u32*   hist = (u32*)  (ws + 0x080000);                 // 1 MB @ 512KB
  u32*   hist2= (u32*)  (ws + 0x180000);                 // 1 KB @ 1.5MB
  u32*   Tbin = (u32*)  (ws + 0x180000 + 1024);
  u32*   cnt  = (u32*)  (ws + 0x180000 + 1028);
  u64*   pk   = (u64*)  (ws + 0x180000 + 4096);          // 32 KB
  u32*   idxo = (u32*)  (ws + 0x180000 + 40960);         // 8 KB
  float* fsum = (float*)(ws + 0x180000 + 49152);         // 1 KB
  float* lf   = (float*)(ws + 0x180000 + 50176);         // 16 KB
  float* fsq  = (float*)(ws + 0x180000 + 66560);         // 4 B
  float* f2   = (float*)(ws + (4ull  << 20));            // 2 MB
  float* f    = (float*)(ws + (6ull  << 20));            // 2 MB
  u16*   h    = (u16*)  (ws + (8ull  << 20));            // 2 MB
  u16*   W1T  = (u16*)  (ws + (10ull << 20));            // 2 MB
  u16*   W2T  = (u16*)  (ws + (12ull << 20));            // 8 MB
  u16*   WoT  = (u16*)  (ws + (20ull << 20));            // 4 MB
  u16*   T1   = (u16*)  (ws + (24ull << 20));            // 8 MB
  u16*   T2   = (u16*)  (ws + (32ull << 20));            // 8 MB -> peak 40 MB

  dim3 blk(256);
  // feature extractor — SCORE-PATH bits FROZEN (32x64 tile, 2x4/thread, 2 blocks/CU)
  gemm_seq_k<1><<<dim3(8, 64), blk, 0, stream>>>(x,  W1, b1, f1, 2048, 512, 2048);
  gemm_seq_k<1><<<dim3(4, 64), blk, 0, stream>>>(f1, W2, b2, f2, 2048, 256, 512);
  gemm_seq_k<0><<<dim3(4, 64), blk, 0, stream>>>(f2, W3, b3, f,  2048, 256, 256);
  hipMemsetAsync(hist, 0, 1048576, stream);
  hipMemsetAsync(ws + 0x180000, 0, 36864, stream);  // hist2,Tbin,cnt,pk
  // frozen score path (2-thread/row split + register preload, bit-exact)
  fsum_seq_k <<<dim3(4),   dim3(64),   0, stream>>>(f, fsum);
  leaf_k     <<<dim3(16),  blk,        0, stream>>>(f, lf);
  tree_k     <<<dim3(1),   dim3(1024), 0, stream>>>(lf, fsq);
  score_row_k<<<dim3(782), blk,        0, stream>>>(mem, fsum, fsq, keys, hist, hist2);
  find_T_k   <<<dim3(1),   dim3(1024), 0, stream>>>(hist, hist2, Tbin);
  compact_k  <<<dim3(391), blk,        0, stream>>>(keys, Tbin, pk, cnt);
  sort_k     <<<dim3(1),   dim3(1024), 0, stream>>>(pk, idxo);
  // concat (bf16) + weight transpose-convert
  build_h_k<<<dim3(2048), blk, 0, stream>>>(f, mem, idxo, h);
  convT_k<<<dim3(64, 16), dim3(32, 8), 0, stream>>>(Wt1, W1T, 512,  2048);
  convT_k<<<dim3(64, 64), dim3(32, 8), 0, stream>>>(Wt2, W2T, 2048, 2048);
  convT_k<<<dim3(32, 64), dim3(32, 8), 0, stream>>>(Wo,  WoT, 2048, 1024);
  // task column — bf16 MFMA
  gemm_bf16_k<1, 1><<<dim3(16, 16), blk, 0, stream>>>(h,  W1T, bt1, T1, 2048, 2048, 512);
  gemm_bf16_k<1, 1><<<dim3(16, 16), blk, 0, stream>>>(T1, W2T, bt2, T2, 2048, 2048, 2048);
  gemm_bf16_k<0, 0><<<dim3(8, 16),  blk, 0, stream>>>(T2, WoT, bo, (float*)d_out, 2048, 1024, 2048);
}

// Round 16
// 459.456 us; speedup vs baseline: 1.0491x; 1.0491x over previous
//
#include <hip/hip_runtime.h>

typedef unsigned int u32;
typedef unsigned long long u64;
typedef unsigned short u16;

typedef __attribute__((ext_vector_type(8))) short bf16x8;
typedef __attribute__((ext_vector_type(4))) float f32x4;

#define FEAT 256
#define MEMN 100000

// Prevent fp contraction (hipcc defaults -ffp-contract=fast).
#define OPAQ(x) asm volatile("" : "+v"(x))

static __device__ __forceinline__ u16 f2bf(float x){   // round-to-nearest-even
  u32 u = __float_as_uint(x);
  u32 r = u + 0x7fffu + ((u >> 16) & 1u);
  return (u16)(r >> 16);
}

// ---------------- f32 GEMM panel kernel, OpenBLAS-replica bits -------------------------
// Computes ONE kc-panel's ascending-k FMA chain per output (the exact chain the frozen
// kernel accumulated between flushes) and stores the RAW panel sum. 64x64 tile,
// 4x4/thread (best measured: 2 b128 LDS reads per 16 FMA), 256 thr. K-split gives
// grid = tiles x panels: G1 = (8,32,6) = 1536 blocks -> 4-6 blocks/CU (vs 1).
__global__ __launch_bounds__(256) void gemm_panel_k(const float* __restrict__ A,
                                                    const float* __restrict__ Bm,
                                                    float* __restrict__ Ppart,
                                                    int M, int N, int K){
  __shared__ float At[2][32][68];   // [buf][k][row]
  __shared__ float Bs[2][32][68];   // [buf][k][col]
  const int t = threadIdx.x;
  const int tx = t & 15, ty = t >> 4;
  const int bm = blockIdx.y << 6, bn = blockIdx.x << 6;
  const int p  = blockIdx.z;
  const int k0 = p * 384;
  const int k1 = (k0 + 384 < K) ? (k0 + 384) : K;
  float* Pout = Ppart + (u64)p * M * N;
  float acc[4][4];
  #pragma unroll
  for (int i = 0; i < 4; i++)
    #pragma unroll
    for (int j = 0; j < 4; j++) acc[i][j] = 0.f;

  float pa[8], pb[8];
  #pragma unroll
  for (int i = 0; i < 8; i++){
    int o = t + (i << 8);
    pa[i] = A [(u64)(bm + (o >> 5)) * K + k0 + (o & 31)];
    pb[i] = Bm[(u64)(k0 + (o >> 6)) * N + bn + (o & 63)];
  }
  #pragma unroll
  for (int i = 0; i < 8; i++){
    int o = t + (i << 8);
    At[0][o & 31][o >> 5] = pa[i];
    Bs[0][o >> 6][o & 63] = pb[i];
  }
  __syncthreads();

  int cur = 0;
  for (int kt = k0; kt < k1; kt += 32){
    const int nxt = kt + 32;
    if (nxt < k1){
      #pragma unroll
      for (int i = 0; i < 8; i++){
        int o = t + (i << 8);
        pa[i] = A [(u64)(bm + (o >> 5)) * K + nxt + (o & 31)];
        pb[i] = Bm[(u64)(nxt + (o >> 6)) * N + bn + (o & 63)];
      }
    }
    #pragma unroll
    for (int k = 0; k < 32; k++){    // ascending k: frozen chain
      float4 av = *reinterpret_cast<const float4*>(&At[cur][k][ty << 2]);
      float4 bv = *reinterpret_cast<const float4*>(&Bs[cur][k][tx << 2]);
      acc[0][0] = fmaf(av.x, bv.x, acc[0][0]); acc[0][1] = fmaf(av.x, bv.y, acc[0][1]);
      acc[0][2] = fmaf(av.x, bv.z, acc[0][2]); acc[0][3] = fmaf(av.x, bv.w, acc[0][3]);
      acc[1][0] = fmaf(av.y, bv.x, acc[1][0]); acc[1][1] = fmaf(av.y, bv.y, acc[1][1]);
      acc[1][2] = fmaf(av.y, bv.z, acc[1][2]); acc[1][3] = fmaf(av.y, bv.w, acc[1][3]);
      acc[2][0] = fmaf(av.z, bv.x, acc[2][0]); acc[2][1] = fmaf(av.z, bv.y, acc[2][1]);
      acc[2][2] = fmaf(av.z, bv.z, acc[2][2]); acc[2][3] = fmaf(av.z, bv.w, acc[2][3]);
      acc[3][0] = fmaf(av.w, bv.x, acc[3][0]); acc[3][1] = fmaf(av.w, bv.y, acc[3][1]);
      acc[3][2] = fmaf(av.w, bv.z, acc[3][2]); acc[3][3] = fmaf(av.w, bv.w, acc[3][3]);
    }
    if (nxt < k1){
      #pragma unroll
      for (int i = 0; i < 8; i++){
        int o = t + (i << 8);
        At[cur ^ 1][o & 31][o >> 5] = pa[i];
        Bs[cur ^ 1][o >> 6][o & 63] = pb[i];
      }
      __syncthreads();
      cur ^= 1;
    }
  }
  #pragma unroll
  for (int i = 0; i < 4; i++){
    int row = bm + (ty << 2) + i;
    #pragma unroll
    for (int j = 0; j < 4; j++){
      int col = bn + (tx << 2) + j;
      Pout[(u64)row * N + col] = acc[i][j];    // raw panel sum (no bias/relu)
    }
  }
}

// ---------------- combine panels left-assoc (replicates mast=0; mast+=acc_p ...) -------
template<int NP, int RELU>
__global__ __launch_bounds__(256) void combine_k(const float* __restrict__ Ppart,
                                                 const float* __restrict__ bias,
                                                 float* __restrict__ C,
                                                 int N, u64 pstride){
  u64 i = (u64)blockIdx.x * 256 + threadIdx.x;
  float v = 0.0f + Ppart[i];       // mast = 0 + p0 (exact, incl -0 corner)
  OPAQ(v);
  #pragma unroll
  for (int p = 1; p < NP; p++){ v = v + Ppart[p * pstride + i]; }
  v = v + bias[(int)(i % (u64)N)];
  if (RELU) v = v > 0.f ? v : 0.f;
  C[i] = v;
}

// ---------------- f_sum: sequential f32 over rows (frozen chains; 4 blocks) ------------
__global__ __launch_bounds__(64) void fsum_seq_k(const float* __restrict__ f,
                                                 float* __restrict__ fsum){
  int d = (blockIdx.x << 6) + threadIdx.x;
  float s = 0.f;
  for (int r = 0; r < 2048; r++) s += f[(u64)r * FEAT + d];
  fsum[d] = s;
}

// ==== numpy npyv-AVX512 pairwise base case for one 128-block of SQUARES (frozen) =======
__device__ __forceinline__ float block128_sq_avx512(const float4* base, int off, int swz){
  float e0[16], e1[16], f0[16], s16[16];
  #pragma unroll
  for (int j = 0; j < 8; j++){
    #pragma unroll
    for (int q = 0; q < 4; q++){
      float4 v = base[off + (((j << 2) + q) ^ swz)];
      float p0 = v.x * v.x, p1 = v.y * v.y, p2 = v.z * v.z, p3 = v.w * v.w;
      OPAQ(p0); OPAQ(p1); OPAQ(p2); OPAQ(p3);
      int l = q << 2;
      if (j == 0 || j == 4){ e0[l] = p0; e0[l+1] = p1; e0[l+2] = p2; e0[l+3] = p3; }
      else if (j == 1 || j == 5){ e0[l] += p0; e0[l+1] += p1; e0[l+2] += p2; e0[l+3] += p3; }
      else if (j == 2 || j == 6){ e1[l] = p0; e1[l+1] = p1; e1[l+2] = p2; e1[l+3] = p3; }
      else { e1[l] += p0; e1[l+1] += p1; e1[l+2] += p2; e1[l+3] += p3; }
    }
    if (j == 3){
      #pragma unroll
      for (int l = 0; l < 16; l++) f0[l] = e0[l] + e1[l];
    }
    if (j == 7){
      #pragma unroll
      for (int l = 0; l < 16; l++) s16[l] = f0[l] + (e0[l] + e1[l]);
    }
  }
  float h8[8], h4[4], h2[2];
  #pragma unroll
  for (int l = 0; l < 8; l++) h8[l] = s16[l] + s16[l + 8];
  #pragma unroll
  for (int l = 0; l < 4; l++) h4[l] = h8[l] + h8[l + 4];
  h2[0] = h4[0] + h4[2]; h2[1] = h4[1] + h4[3];
  return h2[0] + h2[1];
}

// ---------------- f_sq leaves + combine (frozen) ---------------------------------------
__global__ __launch_bounds__(256) void leaf_k(const float* __restrict__ f,
                                              float* __restrict__ lf){
  int b = blockIdx.x * 256 + threadIdx.x;
  lf[b] = block128_sq_avx512((const float4*)(f + (u64)b * 128), 0, 0);
}

__global__ __launch_bounds__(1024) void tree_k(const float* __restrict__ lf,
                                               float* __restrict__ fsq){
  __shared__ float sa[4096];
  __shared__ float sb[2048];
  int t = threadIdx.x;
  for (int i = t; i < 4096; i += 1024) sa[i] = lf[i];
  __syncthreads();
  float* src = sa; float* dst = sb;
  for (int len = 2048; len >= 1; len >>= 1){
    for (int i = t; i < len; i += 1024) dst[i] = src[2 * i] + src[2 * i + 1];
    __syncthreads();
    float* tmp = src; src = dst; dst = tmp;
  }
  if (t == 0) *fsq = src[0];
}

// ---------------- per-row score: 2 threads/row + 16-wide register preload (frozen) -----
__global__ __launch_bounds__(256) void score_row_k(const float* __restrict__ mem,
                                                   const float* __restrict__ fsum,
                                                   const float* __restrict__ fsq_p,
                                                   u32* __restrict__ keys,
                                                   u32* __restrict__ hist,
                                                   u32* __restrict__ hist2){
  __shared__ __align__(16) float fs[256];
  __shared__ u32 lh2[256];
  const int t = threadIdx.x;
  fs[t] = fsum[t];
  lh2[t] = 0;
  __syncthreads();
  const int sub = t & 1;
  const int row = (blockIdx.x << 7) + (t >> 1);
  float key_s = 0.f; bool live = (row < MEMN);
  if (live){
    const float4* rowp = (const float4*)(mem + (u64)row * FEAT);
    const float4* s4 = (const float4*)fs;
    float dpr[4];
    #pragma unroll
    for (int j = 0; j < 4; j++) dpr[j] = 0.f;
    float msqh[2];
    #pragma unroll
    for (int blk = 0; blk < 2; blk++){
      const int off = blk << 5;
      float4 mvv[16];
      #pragma unroll
      for (int j = 0; j < 8; j++)
        #pragma unroll
        for (int cs = 0; cs < 2; cs++)
          mvv[(j << 1) | cs] = rowp[off + (j << 2) + sub + (cs << 1)];
      float e0L[8], e1L[8], f0L[8], s16L[8];
      #pragma unroll
      for (int j = 0; j < 8; j++){
        #pragma unroll
        for (int cs = 0; cs < 2; cs++){
          int kb = off + (j << 2) + sub + (cs << 1);
          float4 v = mvv[(j << 1) | cs];
          float4 fv = s4[kb];
          float p0 = v.x * v.x, p1 = v.y * v.y, p2 = v.z * v.z, p3 = v.w * v.w;
          OPAQ(p0); OPAQ(p1); OPAQ(p2); OPAQ(p3);
          int li = cs << 2;
          if (j == 0 || j == 4){ e0L[li] = p0; e0L[li+1] = p1; e0L[li+2] = p2; e0L[li+3] = p3; }
          else if (j == 1 || j == 5){ e0L[li] += p0; e0L[li+1] += p1; e0L[li+2] += p2; e0L[li+3] += p3; }
          else if (j == 2 || j == 6){ e1L[li] = p0; e1L[li+1] = p1; e1L[li+2] = p2; e1L[li+3] = p3; }
          else { e1L[li] += p0; e1L[li+1] += p1; e1L[li+2] += p2; e1L[li+3] += p3; }
          dpr[0] = fmaf(v.x, fv.x, dpr[0]);
          dpr[1] = fmaf(v.y, fv.y, dpr[1]);
          dpr[2] = fmaf(v.z, fv.z, dpr[2]);
          dpr[3] = fmaf(v.w, fv.w, dpr[3]);
        }
        if (j == 3){
          #pragma unroll
          for (int l = 0; l < 8; l++) f0L[l] = e0L[l] + e1L[l];
        }
        if (j == 7){
          #pragma unroll
          for (int l = 0; l < 8; l++) s16L[l] = f0L[l] + (e0L[l] + e1L[l]);
        }
      }
      float h8L[4], oth[4], h4v[4];
      #pragma unroll
      for (int l = 0; l < 4; l++) h8L[l] = s16L[l] + s16L[4 + l];
      #pragma unroll
      for (int l = 0; l < 4; l++) oth[l] = __shfl_xor(h8L[l], 1);
      #pragma unroll
      for (int l = 0; l < 4; l++) h4v[l] = h8L[l] + oth[l];    // commutative: same bits
      float h2a = h4v[0] + h4v[2], h2b = h4v[1] + h4v[3];
      msqh[blk] = h2a + h2b;
    }
    float msq = msqh[0] + msqh[1];
    float od[4];
    #pragma unroll
    for (int i = 0; i < 4; i++) od[i] = __shfl_xor(dpr[i], 1);
    float b0 = dpr[0] + od[0], b1 = dpr[1] + od[1];
    float b2 = dpr[2] + od[2], b3 = dpr[3] + od[3];
    float dp = (b0 + b1) + (b2 + b3);
    float t1 = 2048.0f * msq;
    float t2 = 2.0f * dp;
    float d3 = t1 - t2;  OPAQ(d3);
    float d4 = d3 + fsq_p[0];
    key_s = -d4;
  }
  if (live && sub == 0){
    u32 bb = __float_as_uint(key_s);
    u32 key = (bb & 0x80000000u) ? ~bb : (bb | 0x80000000u);
    keys[row] = key;
    atomicAdd(&hist[key >> 14], 1u);
    atomicAdd(&lh2[key >> 24], 1u);
  }
  __syncthreads();
  u32 v = lh2[t];
  if (v) atomicAdd(&hist2[t], v);
}

// ---------------- threshold fine-bin: count(bins >= T) >= 2048 -------------------------
__global__ __launch_bounds__(1024) void find_T_k(const u32* __restrict__ hist,
                                                 const u32* __restrict__ hist2,
                                                 u32* __restrict__ Tbin){
  __shared__ u32 h2[256];
  __shared__ int sh_c;
  __shared__ u32 sh_run;
  __shared__ u32 sa[1024], sb[1024];
  int t = threadIdx.x;
  if (t < 256) h2[t] = hist2[t];
  __syncthreads();
  if (t == 0){
    u32 run = 0; int cstar = 0;
    for (int c = 255; c >= 0; c--){
      u32 v = h2[c];
      if (run + v >= 2048u){ cstar = c; break; }
      run += v;
    }
    sh_c = cstar; sh_run = run;
  }
  __syncthreads();
  int cstar = sh_c; u32 run = sh_run;
  sa[t] = hist[cstar * 1024 + t];
  __syncthreads();
  u32* src = sa; u32* dst = sb;
  for (int off = 1; off < 1024; off <<= 1){
    u32 v = src[t];
    if (t + off < 1024) v += src[t + off];
    dst[t] = v;
    __syncthreads();
    u32* tmp = src; src = dst; dst = tmp;
  }
  u32 suf  = src[t];
  u32 sufn = (t < 1023) ? src[t + 1] : 0u;
  if (run + suf >= 2048u && !(run + sufn >= 2048u)) *Tbin = (u32)(cstar * 1024 + t);
}

// ---------------- compact candidates into packed (key desc, idx asc) u64 ---------------
__global__ __launch_bounds__(256) void compact_k(const u32* __restrict__ keys,
                                                 const u32* __restrict__ Tbin,
                                                 u64* __restrict__ pk,
                                                 u32* __restrict__ counter){
  int i = blockIdx.x * 256 + threadIdx.x;
  if (i >= MEMN) return;
  u32 k = keys[i];
  if ((k >> 14) >= *Tbin){
    u32 p = atomicAdd(counter, 1u);
    if (p < 4096u) pk[p] = ((u64)k << 32) | (u32)(0xFFFFFFFFu - (u32)i);
  }
}

// ---------------- one-block bitonic sort of 4096 u64 desc ------------------------------
__global__ __launch_bounds__(1024) void sort_k(const u64* __restrict__ pkin,
                                               u32* __restrict__ idxo){
  __shared__ u64 k[4096];
  for (int i = threadIdx.x; i < 4096; i += 1024) k[i] = pkin[i];
  __syncthreads();
  for (int size = 2; size <= 4096; size <<= 1){
    for (int stride = size >> 1; stride; stride >>= 1){
      #pragma unroll 2
      for (int pp = 0; pp < 2; pp++){
        int p = threadIdx.x + pp * 1024;
        int i = ((p / stride) * (stride << 1)) + (p % stride);
        int j = i + stride;
        u64 a = k[i], b = k[j];
        bool desc_ok = (a >= b);
        bool up = ((i & size) == 0);
        if (up ? !desc_ok : desc_ok){ k[i] = b; k[j] = a; }
      }
      __syncthreads();
    }
  }
  for (int i = threadIdx.x; i < 2048; i += 1024) idxo[i] = 0xFFFFFFFFu - (u32)k[i];
}

// ---------------- h = concat(f, memory[idx]) -> bf16 -----------------------------------
__global__ __launch_bounds__(256) void build_h_k(const float* __restrict__ f,
                                                 const float* __restrict__ mem,
                                                 const u32* __restrict__ idx,
                                                 u16* __restrict__ h){
  int r = blockIdx.x, t = threadIdx.x;
  h[(u64)r * 512 + t] = f2bf(f[(u64)r * FEAT + t]);
  h[(u64)r * 512 + 256 + t] = f2bf(mem[(u64)idx[r] * FEAT + t]);
}

// ---------------- transpose-convert W[K,N] f32 -> WT[N,K] bf16 -------------------------
__global__ void convT_k(const float* __restrict__ W, u16* __restrict__ WT, int K, int N){
  __shared__ float tile[32][33];
  int tx = threadIdx.x, ty = threadIdx.y;  // blockDim (32,8)
  int bk = blockIdx.y << 5, bn = blockIdx.x << 5;
  #pragma unroll
  for (int i = 0; i < 4; i++){
    int r = ty + (i << 3);
    tile[r][tx] = W[(u64)(bk + r) * N + bn + tx];
  }
  __syncthreads();
  #pragma unroll
  for (int i = 0; i < 4; i++){
    int n = ty + (i << 3);
    WT[(u64)(bn + n) * K + bk + tx] = f2bf(tile[tx][n]);
  }
}

// ---------------- bf16 MFMA GEMM (m97 template): C = act(A @ BT^T + bias) --------------
static __device__ __forceinline__ void gl_lds16(const u16* g, u16* l){
  __builtin_amdgcn_global_load_lds((const __attribute__((address_space(1))) void*)g,
                                   (__attribute__((address_space(3))) void*)l, 16, 0, 0);
}

template<int RELU, int OUTBF>
__global__ __launch_bounds__(256) void gemm_bf16_k(const u16* __restrict__ A,
                                                   const u16* __restrict__ BT,
                                                   const float* __restrict__ bias,
                                                   void* __restrict__ Cout,
                                                   int M, int N, int K){
  __shared__ u16 As[128 * 32];
  __shared__ u16 Bs[128 * 32];
  const int t = threadIdx.x;
  const int w = t >> 6, lane = t & 63;
  const int bm = blockIdx.y << 7, bn = blockIdx.x << 7;
  f32x4 acc[4][4];
  #pragma unroll
  for (int i = 0; i < 4; i++)
    #pragma unroll
    for (int j = 0; j < 4; j++) acc[i][j] = (f32x4){0.f, 0.f, 0.f, 0.f};
  const int row0 = (w >> 1) << 6, col0 = (w & 1) << 6;
  for (int kt = 0; kt < K; kt += 32){
    #pragma unroll
    for (int j = 0; j < 2; j++){
      int e = (((j << 2) + w) << 9) + (lane << 3);
      int r = e >> 5, c = e & 31;
      gl_lds16(A  + (u64)(bm + r) * K + kt + c, As + (((j << 2) + w) << 9));
      gl_lds16(BT + (u64)(bn + r) * K + kt + c, Bs + (((j << 2) + w) << 9));
    }
    __syncthreads();
    bf16x8 af[4], bfr[4];
    #pragma unroll
    for (int i = 0; i < 4; i++){
      af[i]  = *(const bf16x8*)(As + (row0 + (i << 4) + (lane & 15)) * 32 + ((lane >> 4) << 3));
      bfr[i] = *(const bf16x8*)(Bs + (col0 + (i << 4) + (lane & 15)) * 32 + ((lane >> 4) << 3));
    }
    #pragma unroll
    for (int i = 0; i < 4; i++)
      #pragma unroll
      for (int j = 0; j < 4; j++)
        acc[i][j] = __builtin_amdgcn_mfma_f32_16x16x32_bf16(af[i], bfr[j], acc[i][j], 0, 0, 0);
    __syncthreads();
  }
  #pragma unroll
  for (int i = 0; i < 4; i++){
    #pragma unroll
    for (int j = 0; j < 4; j++){
      #pragma unroll
      for (int r = 0; r < 4; r++){
        int row = bm + row0 + (i << 4) + ((lane >> 4) << 2) + r;
        int col = bn + col0 + (j << 4) + (lane & 15);
        float v = acc[i][j][r] + bias[col];
        if (RELU) v = v > 0.f ? v : 0.f;
        if (OUTBF) ((u16*)Cout)[(u64)row * N + col] = f2bf(v);
        else       ((float*)Cout)[(u64)row * N + col] = v;
      }
    }
  }
}

// ======================================================================================
extern "C" void kernel_launch(void* const* d_in, const int* in_sizes, int n_in,
                              void* d_out, int out_size, void* d_ws, size_t ws_size,
                              hipStream_t stream){
  const float* x   = (const float*)d_in[0];
  const float* W1  = (const float*)d_in[1];
  const float* b1  = (const float*)d_in[2];
  const float* W2  = (const float*)d_in[3];
  const float* b2  = (const float*)d_in[4];
  const float* W3  = (const float*)d_in[5];
  const float* b3  = (const float*)d_in[6];
  const float* mem = (const float*)d_in[7];
  const float* Wt1 = (const float*)d_in[8];
  const float* bt1 = (const float*)d_in[9];
  const float* Wt2 = (const float*)d_in[10];
  const float* bt2 = (const float*)d_in[11];
  const float* Wo  = (const float*)d_in[12];
  const float* bo  = (const float*)d_in[13];

  char* ws = (char*)d_ws;
  float* f1   = (float*)(ws + 0);
  u32*   keys = (u32*)  (ws + 0);                        // 400 KB (dead-f1 reuse)
  u32*   hist = (u32*)  (ws + 0x080000);                 // 1 MB @ 512KB
  u32*   hist2= (u32*)  (ws + 0x180000);                 // 1 KB @ 1.5MB
  u32*   Tbin = (u32*)  (ws + 0x180000 + 1024);
  u32*   cnt  = (u32*)  (ws + 0x180000 + 1028);
  u64*   pk   = (u64*)  (ws + 0x180000 + 4096);          // 32 KB
  u32*   idxo = (u32*)  (ws + 0x180000 + 40960);         // 8 KB
  float* fsum = (float*)(ws + 0x180000 + 49152);         // 1 KB
  float* lf   = (float*)(ws + 0x180000 + 50176);         // 16 KB
  float* fsq  = (float*)(ws + 0x180000 + 66560);         // 4 B
  float* f2   = (float*)(ws + (4ull  << 20));            // 2 MB
  float* f    = (float*)(ws + (6ull  << 20));            // 2 MB
  u16*   h    = (u16*)  (ws + (8ull  << 20));            // 2 MB
  u16*   W1T  = (u16*)  (ws + (10ull << 20));            // 2 MB
  u16*   W2T  = (u16*)  (ws + (12ull << 20));            // 8 MB
  u16*   WoT  = (u16*)  (ws + (20ull << 20));            // 4 MB
  u16*   T1   = (u16*)  (ws + (24ull << 20));            // 8 MB
  u16*   T2   = (u16*)  (ws + (32ull << 20));            // 8 MB -> peak 40 MB
  // Panel scratch lives in the W2T/WoT/T1/T2 region (dead until after score path):
  float* Pg1  = (float*)(ws + (12ull << 20));            // 6 x 4 MB = [12,36)
  float* Pg2  = (float*)(ws + (36ull << 20));            // 2 x 2 MB = [36,40)
  float* Pg3  = (float*)(ws + (36ull << 20));            // 1 x 2 MB (reused after G2)

  dim3 blk(256);
  // feature extractor — SCORE-PATH bits FROZEN; K-split panels for CU coverage
  gemm_panel_k<<<dim3(8, 32, 6), blk, 0, stream>>>(x,  W1, Pg1, 2048, 512, 2048);
  combine_k<6, 1><<<dim3(4096), blk, 0, stream>>>(Pg1, b1, f1, 512, (u64)2048 * 512);
  gemm_panel_k<<<dim3(4, 32, 2), blk, 0, stream>>>(f1, W2, Pg2, 2048, 256, 512);
  combine_k<2, 1><<<dim3(2048), blk, 0, stream>>>(Pg2, b2, f2, 256, (u64)2048 * 256);
  gemm_panel_k<<<dim3(4, 32, 1), blk, 0, stream>>>(f2, W3, Pg3, 2048, 256, 256);
  combine_k<1, 0><<<dim3(2048), blk, 0, stream>>>(Pg3, b3, f,  256, (u64)2048 * 256);
  hipMemsetAsync(hist, 0, 1048576, stream);
  hipMemsetAsync(ws + 0x180000, 0, 36864, stream);  // hist2,Tbin,cnt,pk
  // frozen score path (2-thread/row split + register preload, bit-exact)
  fsum_seq_k <<<dim3(4),   dim3(64),   0, stream>>>(f, fsum);
  leaf_k     <<<dim3(16),  blk,        0, stream>>>(f, lf);
  tree_k     <<<dim3(1),   dim3(1024), 0, stream>>>(lf, fsq);
  score_row_k<<<dim3(782), blk,        0, stream>>>(mem, fsum, fsq, keys, hist, hist2);
  find_T_k   <<<dim3(1),   dim3(1024), 0, stream>>>(hist, hist2, Tbin);
  compact_k  <<<dim3(391), blk,        0, stream>>>(keys, Tbin, pk, cnt);
  sort_k     <<<dim3(1),   dim3(1024), 0, stream>>>(pk, idxo);
  // concat (bf16) + weight transpose-convert
  build_h_k<<<dim3(2048), blk, 0, stream>>>(f, mem, idxo, h);
  convT_k<<<dim3(64, 16), dim3(32, 8), 0, stream>>>(Wt1, W1T, 512,  2048);
  convT_k<<<dim3(64, 64), dim3(32, 8), 0, stream>>>(Wt2, W2T, 2048, 2048);
  convT_k<<<dim3(32, 64), dim3(32, 8), 0, stream>>>(Wo,  WoT, 2048, 1024);
  // task column — bf16 MFMA
  gemm_bf16_k<1, 1><<<dim3(16, 16), blk, 0, stream>>>(h,  W1T, bt1, T1, 2048, 2048, 512);
  gemm_bf16_k<1, 1><<<dim3(16, 16), blk, 0, stream>>>(T1, W2T, bt2, T2, 2048, 2048, 2048);
  gemm_bf16_k<0, 0><<<dim3(8, 16),  blk, 0, stream>>>(T2, WoT, bo, (float*)d_out, 2048, 1024, 2048);
}

// Round 17
// 455.521 us; speedup vs baseline: 1.0582x; 1.0086x over previous
//
#include <hip/hip_runtime.h>

typedef unsigned int u32;
typedef unsigned long long u64;
typedef unsigned short u16;

typedef __attribute__((ext_vector_type(8))) short bf16x8;
typedef __attribute__((ext_vector_type(4))) float f32x4;

#define FEAT 256
#define MEMN 100000

// Prevent fp contraction (hipcc defaults -ffp-contract=fast).
#define OPAQ(x) asm volatile("" : "+v"(x))

static __device__ __forceinline__ u16 f2bf(float x){   // round-to-nearest-even
  u32 u = __float_as_uint(x);
  u32 r = u + 0x7fffu + ((u >> 16) & 1u);
  return (u16)(r >> 16);
}

// ---------------- f32 GEMM panel kernel, OpenBLAS-replica bits (r16, kept) -------------
__global__ __launch_bounds__(256) void gemm_panel_k(const float* __restrict__ A,
                                                    const float* __restrict__ Bm,
                                                    float* __restrict__ Ppart,
                                                    int M, int N, int K){
  __shared__ float At[2][32][68];   // [buf][k][row]
  __shared__ float Bs[2][32][68];   // [buf][k][col]
  const int t = threadIdx.x;
  const int tx = t & 15, ty = t >> 4;
  const int bm = blockIdx.y << 6, bn = blockIdx.x << 6;
  const int p  = blockIdx.z;
  const int k0 = p * 384;
  const int k1 = (k0 + 384 < K) ? (k0 + 384) : K;
  float* Pout = Ppart + (u64)p * M * N;
  float acc[4][4];
  #pragma unroll
  for (int i = 0; i < 4; i++)
    #pragma unroll
    for (int j = 0; j < 4; j++) acc[i][j] = 0.f;

  float pa[8], pb[8];
  #pragma unroll
  for (int i = 0; i < 8; i++){
    int o = t + (i << 8);
    pa[i] = A [(u64)(bm + (o >> 5)) * K + k0 + (o & 31)];
    pb[i] = Bm[(u64)(k0 + (o >> 6)) * N + bn + (o & 63)];
  }
  #pragma unroll
  for (int i = 0; i < 8; i++){
    int o = t + (i << 8);
    At[0][o & 31][o >> 5] = pa[i];
    Bs[0][o >> 6][o & 63] = pb[i];
  }
  __syncthreads();

  int cur = 0;
  for (int kt = k0; kt < k1; kt += 32){
    const int nxt = kt + 32;
    if (nxt < k1){
      #pragma unroll
      for (int i = 0; i < 8; i++){
        int o = t + (i << 8);
        pa[i] = A [(u64)(bm + (o >> 5)) * K + nxt + (o & 31)];
        pb[i] = Bm[(u64)(nxt + (o >> 6)) * N + bn + (o & 63)];
      }
    }
    #pragma unroll
    for (int k = 0; k < 32; k++){    // ascending k: frozen chain
      float4 av = *reinterpret_cast<const float4*>(&At[cur][k][ty << 2]);
      float4 bv = *reinterpret_cast<const float4*>(&Bs[cur][k][tx << 2]);
      acc[0][0] = fmaf(av.x, bv.x, acc[0][0]); acc[0][1] = fmaf(av.x, bv.y, acc[0][1]);
      acc[0][2] = fmaf(av.x, bv.z, acc[0][2]); acc[0][3] = fmaf(av.x, bv.w, acc[0][3]);
      acc[1][0] = fmaf(av.y, bv.x, acc[1][0]); acc[1][1] = fmaf(av.y, bv.y, acc[1][1]);
      acc[1][2] = fmaf(av.y, bv.z, acc[1][2]); acc[1][3] = fmaf(av.y, bv.w, acc[1][3]);
      acc[2][0] = fmaf(av.z, bv.x, acc[2][0]); acc[2][1] = fmaf(av.z, bv.y, acc[2][1]);
      acc[2][2] = fmaf(av.z, bv.z, acc[2][2]); acc[2][3] = fmaf(av.z, bv.w, acc[2][3]);
      acc[3][0] = fmaf(av.w, bv.x, acc[3][0]); acc[3][1] = fmaf(av.w, bv.y, acc[3][1]);
      acc[3][2] = fmaf(av.w, bv.z, acc[3][2]); acc[3][3] = fmaf(av.w, bv.w, acc[3][3]);
    }
    if (nxt < k1){
      #pragma unroll
      for (int i = 0; i < 8; i++){
        int o = t + (i << 8);
        At[cur ^ 1][o & 31][o >> 5] = pa[i];
        Bs[cur ^ 1][o >> 6][o & 63] = pb[i];
      }
      __syncthreads();
      cur ^= 1;
    }
  }
  #pragma unroll
  for (int i = 0; i < 4; i++){
    int row = bm + (ty << 2) + i;
    #pragma unroll
    for (int j = 0; j < 4; j++){
      int col = bn + (tx << 2) + j;
      Pout[(u64)row * N + col] = acc[i][j];    // raw panel sum (no bias/relu)
    }
  }
}

// ---------------- combine panels left-assoc (replicates mast=0; mast+=acc_p ...) -------
template<int NP, int RELU>
__global__ __launch_bounds__(256) void combine_k(const float* __restrict__ Ppart,
                                                 const float* __restrict__ bias,
                                                 float* __restrict__ C,
                                                 int N, u64 pstride){
  u64 i = (u64)blockIdx.x * 256 + threadIdx.x;
  float v = 0.0f + Ppart[i];       // mast = 0 + p0 (exact, incl -0 corner)
  OPAQ(v);
  #pragma unroll
  for (int p = 1; p < NP; p++){ v = v + Ppart[p * pstride + i]; }
  v = v + bias[(int)(i % (u64)N)];
  if (RELU) v = v > 0.f ? v : 0.f;
  C[i] = v;
}

// ---------------- f_sum: sequential f32 over rows (frozen chains; 4 blocks) ------------
__global__ __launch_bounds__(64) void fsum_seq_k(const float* __restrict__ f,
                                                 float* __restrict__ fsum){
  int d = (blockIdx.x << 6) + threadIdx.x;
  float s = 0.f;
  for (int r = 0; r < 2048; r++) s += f[(u64)r * FEAT + d];
  fsum[d] = s;
}

// ==== numpy npyv-AVX512 pairwise base case for one 128-block of SQUARES (frozen) =======
__device__ __forceinline__ float block128_sq_avx512(const float4* base, int off, int swz){
  float e0[16], e1[16], f0[16], s16[16];
  #pragma unroll
  for (int j = 0; j < 8; j++){
    #pragma unroll
    for (int q = 0; q < 4; q++){
      float4 v = base[off + (((j << 2) + q) ^ swz)];
      float p0 = v.x * v.x, p1 = v.y * v.y, p2 = v.z * v.z, p3 = v.w * v.w;
      OPAQ(p0); OPAQ(p1); OPAQ(p2); OPAQ(p3);
      int l = q << 2;
      if (j == 0 || j == 4){ e0[l] = p0; e0[l+1] = p1; e0[l+2] = p2; e0[l+3] = p3; }
      else if (j == 1 || j == 5){ e0[l] += p0; e0[l+1] += p1; e0[l+2] += p2; e0[l+3] += p3; }
      else if (j == 2 || j == 6){ e1[l] = p0; e1[l+1] = p1; e1[l+2] = p2; e1[l+3] = p3; }
      else { e1[l] += p0; e1[l+1] += p1; e1[l+2] += p2; e1[l+3] += p3; }
    }
    if (j == 3){
      #pragma unroll
      for (int l = 0; l < 16; l++) f0[l] = e0[l] + e1[l];
    }
    if (j == 7){
      #pragma unroll
      for (int l = 0; l < 16; l++) s16[l] = f0[l] + (e0[l] + e1[l]);
    }
  }
  float h8[8], h4[4], h2[2];
  #pragma unroll
  for (int l = 0; l < 8; l++) h8[l] = s16[l] + s16[l + 8];
  #pragma unroll
  for (int l = 0; l < 4; l++) h4[l] = h8[l] + h8[l + 4];
  h2[0] = h4[0] + h4[2]; h2[1] = h4[1] + h4[3];
  return h2[0] + h2[1];
}

// ---------------- f_sq leaves + combine (frozen) ---------------------------------------
__global__ __launch_bounds__(256) void leaf_k(const float* __restrict__ f,
                                              float* __restrict__ lf){
  int b = blockIdx.x * 256 + threadIdx.x;
  lf[b] = block128_sq_avx512((const float4*)(f + (u64)b * 128), 0, 0);
}

__global__ __launch_bounds__(1024) void tree_k(const float* __restrict__ lf,
                                               float* __restrict__ fsq){
  __shared__ float sa[4096];
  __shared__ float sb[2048];
  int t = threadIdx.x;
  for (int i = t; i < 4096; i += 1024) sa[i] = lf[i];
  __syncthreads();
  float* src = sa; float* dst = sb;
  for (int len = 2048; len >= 1; len >>= 1){
    for (int i = t; i < len; i += 1024) dst[i] = src[2 * i] + src[2 * i + 1];
    __syncthreads();
    float* tmp = src; src = dst; dst = tmp;
  }
  if (t == 0) *fsq = src[0];
}

// ---------------- per-row score: 2 thr/row, BOTH 16-load batches issued up-front -------
// r16: batch2's loads waited behind block0's compute. Preload all 32 float4s (two
// statically-indexed arrays, +64 VGPR -> ~116 < 128: occupancy unchanged, 2x loads in
// flight). Compute sequence identical -> bit-frozen.
__global__ __launch_bounds__(256) void score_row_k(const float* __restrict__ mem,
                                                   const float* __restrict__ fsum,
                                                   const float* __restrict__ fsq_p,
                                                   u32* __restrict__ keys,
                                                   u32* __restrict__ hist,
                                                   u32* __restrict__ hist2){
  __shared__ __align__(16) float fs[256];
  __shared__ u32 lh2[256];
  const int t = threadIdx.x;
  fs[t] = fsum[t];
  lh2[t] = 0;
  __syncthreads();
  const int sub = t & 1;
  const int row = (blockIdx.x << 7) + (t >> 1);
  float key_s = 0.f; bool live = (row < MEMN);
  if (live){
    const float4* rowp = (const float4*)(mem + (u64)row * FEAT);
    const float4* s4 = (const float4*)fs;
    float4 mvvA[16], mvvB[16];                     // all 32 loads issued before compute
    #pragma unroll
    for (int j = 0; j < 8; j++)
      #pragma unroll
      for (int cs = 0; cs < 2; cs++){
        mvvA[(j << 1) | cs] = rowp[(j << 2) + sub + (cs << 1)];
        mvvB[(j << 1) | cs] = rowp[32 + (j << 2) + sub + (cs << 1)];
      }
    float dpr[4];
    #pragma unroll
    for (int j = 0; j < 4; j++) dpr[j] = 0.f;
    float msqh[2];
    #pragma unroll
    for (int blk = 0; blk < 2; blk++){
      const int off = blk << 5;
      float e0L[8], e1L[8], f0L[8], s16L[8];
      #pragma unroll
      for (int j = 0; j < 8; j++){
        #pragma unroll
        for (int cs = 0; cs < 2; cs++){
          int kb = off + (j << 2) + sub + (cs << 1);
          float4 v = blk ? mvvB[(j << 1) | cs] : mvvA[(j << 1) | cs];
          float4 fv = s4[kb];
          float p0 = v.x * v.x, p1 = v.y * v.y, p2 = v.z * v.z, p3 = v.w * v.w;
          OPAQ(p0); OPAQ(p1); OPAQ(p2); OPAQ(p3);
          int li = cs << 2;
          if (j == 0 || j == 4){ e0L[li] = p0; e0L[li+1] = p1; e0L[li+2] = p2; e0L[li+3] = p3; }
          else if (j == 1 || j == 5){ e0L[li] += p0; e0L[li+1] += p1; e0L[li+2] += p2; e0L[li+3] += p3; }
          else if (j == 2 || j == 6){ e1L[li] = p0; e1L[li+1] = p1; e1L[li+2] = p2; e1L[li+3] = p3; }
          else { e1L[li] += p0; e1L[li+1] += p1; e1L[li+2] += p2; e1L[li+3] += p3; }
          dpr[0] = fmaf(v.x, fv.x, dpr[0]);
          dpr[1] = fmaf(v.y, fv.y, dpr[1]);
          dpr[2] = fmaf(v.z, fv.z, dpr[2]);
          dpr[3] = fmaf(v.w, fv.w, dpr[3]);
        }
        if (j == 3){
          #pragma unroll
          for (int l = 0; l < 8; l++) f0L[l] = e0L[l] + e1L[l];
        }
        if (j == 7){
          #pragma unroll
          for (int l = 0; l < 8; l++) s16L[l] = f0L[l] + (e0L[l] + e1L[l]);
        }
      }
      float h8L[4], oth[4], h4v[4];
      #pragma unroll
      for (int l = 0; l < 4; l++) h8L[l] = s16L[l] + s16L[4 + l];
      #pragma unroll
      for (int l = 0; l < 4; l++) oth[l] = __shfl_xor(h8L[l], 1);
      #pragma unroll
      for (int l = 0; l < 4; l++) h4v[l] = h8L[l] + oth[l];    // commutative: same bits
      float h2a = h4v[0] + h4v[2], h2b = h4v[1] + h4v[3];
      msqh[blk] = h2a + h2b;
    }
    float msq = msqh[0] + msqh[1];
    float od[4];
    #pragma unroll
    for (int i = 0; i < 4; i++) od[i] = __shfl_xor(dpr[i], 1);
    float b0 = dpr[0] + od[0], b1 = dpr[1] + od[1];
    float b2 = dpr[2] + od[2], b3 = dpr[3] + od[3];
    float dp = (b0 + b1) + (b2 + b3);
    float t1 = 2048.0f * msq;
    float t2 = 2.0f * dp;
    float d3 = t1 - t2;  OPAQ(d3);
    float d4 = d3 + fsq_p[0];
    key_s = -d4;
  }
  if (live && sub == 0){
    u32 bb = __float_as_uint(key_s);
    u32 key = (bb & 0x80000000u) ? ~bb : (bb | 0x80000000u);
    keys[row] = key;
    atomicAdd(&hist[key >> 14], 1u);
    atomicAdd(&lh2[key >> 24], 1u);
  }
  __syncthreads();
  u32 v = lh2[t];
  if (v) atomicAdd(&hist2[t], v);
}

// ---------------- threshold fine-bin: count(bins >= T) >= 2048 -------------------------
__global__ __launch_bounds__(1024) void find_T_k(const u32* __restrict__ hist,
                                                 const u32* __restrict__ hist2,
                                                 u32* __restrict__ Tbin){
  __shared__ u32 h2[256];
  __shared__ int sh_c;
  __shared__ u32 sh_run;
  __shared__ u32 sa[1024], sb[1024];
  int t = threadIdx.x;
  if (t < 256) h2[t] = hist2[t];
  __syncthreads();
  if (t == 0){
    u32 run = 0; int cstar = 0;
    for (int c = 255; c >= 0; c--){
      u32 v = h2[c];
      if (run + v >= 2048u){ cstar = c; break; }
      run += v;
    }
    sh_c = cstar; sh_run = run;
  }
  __syncthreads();
  int cstar = sh_c; u32 run = sh_run;
  sa[t] = hist[cstar * 1024 + t];
  __syncthreads();
  u32* src = sa; u32* dst = sb;
  for (int off = 1; off < 1024; off <<= 1){
    u32 v = src[t];
    if (t + off < 1024) v += src[t + off];
    dst[t] = v;
    __syncthreads();
    u32* tmp = src; src = dst; dst = tmp;
  }
  u32 suf  = src[t];
  u32 sufn = (t < 1023) ? src[t + 1] : 0u;
  if (run + suf >= 2048u && !(run + sufn >= 2048u)) *Tbin = (u32)(cstar * 1024 + t);
}

// ---------------- compact candidates into packed (key desc, idx asc) u64 ---------------
__global__ __launch_bounds__(256) void compact_k(const u32* __restrict__ keys,
                                                 const u32* __restrict__ Tbin,
                                                 u64* __restrict__ pk,
                                                 u32* __restrict__ counter){
  int i = blockIdx.x * 256 + threadIdx.x;
  if (i >= MEMN) return;
  u32 k = keys[i];
  if ((k >> 14) >= *Tbin){
    u32 p = atomicAdd(counter, 1u);
    if (p < 4096u) pk[p] = ((u64)k << 32) | (u32)(0xFFFFFFFFu - (u32)i);
  }
}

// ---------------- one-block bitonic sort of 4096 u64 desc ------------------------------
__global__ __launch_bounds__(1024) void sort_k(const u64* __restrict__ pkin,
                                               u32* __restrict__ idxo){
  __shared__ u64 k[4096];
  for (int i = threadIdx.x; i < 4096; i += 1024) k[i] = pkin[i];
  __syncthreads();
  for (int size = 2; size <= 4096; size <<= 1){
    for (int stride = size >> 1; stride; stride >>= 1){
      #pragma unroll 2
      for (int pp = 0; pp < 2; pp++){
        int p = threadIdx.x + pp * 1024;
        int i = ((p / stride) * (stride << 1)) + (p % stride);
        int j = i + stride;
        u64 a = k[i], b = k[j];
        bool desc_ok = (a >= b);
        bool up = ((i & size) == 0);
        if (up ? !desc_ok : desc_ok){ k[i] = b; k[j] = a; }
      }
      __syncthreads();
    }
  }
  for (int i = threadIdx.x; i < 2048; i += 1024) idxo[i] = 0xFFFFFFFFu - (u32)k[i];
}

// ---------------- h = concat(f, memory[idx]) -> bf16 -----------------------------------
__global__ __launch_bounds__(256) void build_h_k(const float* __restrict__ f,
                                                 const float* __restrict__ mem,
                                                 const u32* __restrict__ idx,
                                                 u16* __restrict__ h){
  int r = blockIdx.x, t = threadIdx.x;
  h[(u64)r * 512 + t] = f2bf(f[(u64)r * FEAT + t]);
  h[(u64)r * 512 + 256 + t] = f2bf(mem[(u64)idx[r] * FEAT + t]);
}

// ---------------- transpose-convert W[K,N] f32 -> WT[N,K] bf16 -------------------------
__global__ void convT_k(const float* __restrict__ W, u16* __restrict__ WT, int K, int N){
  __shared__ float tile[32][33];
  int tx = threadIdx.x, ty = threadIdx.y;  // blockDim (32,8)
  int bk = blockIdx.y << 5, bn = blockIdx.x << 5;
  #pragma unroll
  for (int i = 0; i < 4; i++){
    int r = ty + (i << 3);
    tile[r][tx] = W[(u64)(bk + r) * N + bn + tx];
  }
  __syncthreads();
  #pragma unroll
  for (int i = 0; i < 4; i++){
    int n = ty + (i << 3);
    WT[(u64)(bn + n) * K + bk + tx] = f2bf(tile[tx][n]);
  }
}

// ---------------- bf16 MFMA GEMM (m97 template): C = act(A @ BT^T + bias) --------------
static __device__ __forceinline__ void gl_lds16(const u16* g, u16* l){
  __builtin_amdgcn_global_load_lds((const __attribute__((address_space(1))) void*)g,
                                   (__attribute__((address_space(3))) void*)l, 16, 0, 0);
}

template<int RELU, int OUTBF>
__global__ __launch_bounds__(256) void gemm_bf16_k(const u16* __restrict__ A,
                                                   const u16* __restrict__ BT,
                                                   const float* __restrict__ bias,
                                                   void* __restrict__ Cout,
                                                   int M, int N, int K){
  __shared__ u16 As[128 * 32];
  __shared__ u16 Bs[128 * 32];
  const int t = threadIdx.x;
  const int w = t >> 6, lane = t & 63;
  const int bm = blockIdx.y << 7, bn = blockIdx.x << 7;
  f32x4 acc[4][4];
  #pragma unroll
  for (int i = 0; i < 4; i++)
    #pragma unroll
    for (int j = 0; j < 4; j++) acc[i][j] = (f32x4){0.f, 0.f, 0.f, 0.f};
  const int row0 = (w >> 1) << 6, col0 = (w & 1) << 6;
  for (int kt = 0; kt < K; kt += 32){
    #pragma unroll
    for (int j = 0; j < 2; j++){
      int e = (((j << 2) + w) << 9) + (lane << 3);
      int r = e >> 5, c = e & 31;
      gl_lds16(A  + (u64)(bm + r) * K + kt + c, As + (((j << 2) + w) << 9));
      gl_lds16(BT + (u64)(bn + r) * K + kt + c, Bs + (((j << 2) + w) << 9));
    }
    __syncthreads();
    bf16x8 af[4], bfr[4];
    #pragma unroll
    for (int i = 0; i < 4; i++){
      af[i]  = *(const bf16x8*)(As + (row0 + (i << 4) + (lane & 15)) * 32 + ((lane >> 4) << 3));
      bfr[i] = *(const bf16x8*)(Bs + (col0 + (i << 4) + (lane & 15)) * 32 + ((lane >> 4) << 3));
    }
    #pragma unroll
    for (int i = 0; i < 4; i++)
      #pragma unroll
      for (int j = 0; j < 4; j++)
        acc[i][j] = __builtin_amdgcn_mfma_f32_16x16x32_bf16(af[i], bfr[j], acc[i][j], 0, 0, 0);
    __syncthreads();
  }
  #pragma unroll
  for (int i = 0; i < 4; i++){
    #pragma unroll
    for (int j = 0; j < 4; j++){
      #pragma unroll
      for (int r = 0; r < 4; r++){
        int row = bm + row0 + (i << 4) + ((lane >> 4) << 2) + r;
        int col = bn + col0 + (j << 4) + (lane & 15);
        float v = acc[i][j][r] + bias[col];
        if (RELU) v = v > 0.f ? v : 0.f;
        if (OUTBF) ((u16*)Cout)[(u64)row * N + col] = f2bf(v);
        else       ((float*)Cout)[(u64)row * N + col] = v;
      }
    }
  }
}

// ======================================================================================
extern "C" void kernel_launch(void* const* d_in, const int* in_sizes, int n_in,
                              void* d_out, int out_size, void* d_ws, size_t ws_size,
                              hipStream_t stream){
  const float* x   = (const float*)d_in[0];
  const float* W1  = (const float*)d_in[1];
  const float* b1  = (const float*)d_in[2];
  const float* W2  = (const float*)d_in[3];
  const float* b2  = (const float*)d_in[4];
  const float* W3  = (const float*)d_in[5];
  const float* b3  = (const float*)d_in[6];
  const float* mem = (const float*)d_in[7];
  const float* Wt1 = (const float*)d_in[8];
  const float* bt1 = (const float*)d_in[9];
  const float* Wt2 = (const float*)d_in[10];
  const float* bt2 = (const float*)d_in[11];
  const float* Wo  = (const float*)d_in[12];
  const float* bo  = (const float*)d_in[13];

  char* ws = (char*)d_ws;
  float* f1   = (float*)(ws + 0);
  u32*   keys = (u32*)  (ws + 0);                        // 400 KB (dead-f1 reuse)
  u32*   hist = (u32*)  (ws + 0x080000);                 // 1 MB @ 512KB
  u32*   hist2= (u32*)  (ws + 0x180000);                 // 1 KB @ 1.5MB
  u32*   Tbin = (u32*)  (ws + 0x180000 + 1024);
  u32*   cnt  = (u32*)  (ws + 0x180000 + 1028);
  u64*   pk   = (u64*)  (ws + 0x180000 + 4096);          // 32 KB
  u32*   idxo = (u32*)  (ws + 0x180000 + 40960);         // 8 KB
  float* fsum = (float*)(ws + 0x180000 + 49152);         // 1 KB
  float* lf   = (float*)(ws + 0x180000 + 50176);         // 16 KB
  float* fsq  = (float*)(ws + 0x180000 + 66560);         // 4 B
  float* f2   = (float*)(ws + (4ull  << 20));            // 2 MB
  float* f    = (float*)(ws + (6ull  << 20));            // 2 MB
  u16*   h    = (u16*)  (ws + (8ull  << 20));            // 2 MB
  u16*   W1T  = (u16*)  (ws + (10ull << 20));            // 2 MB
  u16*   W2T  = (u16*)  (ws + (12ull << 20));            // 8 MB
  u16*   WoT  = (u16*)  (ws + (20ull << 20));            // 4 MB
  u16*   T1   = (u16*)  (ws + (24ull << 20));            // 8 MB
  u16*   T2   = (u16*)  (ws + (32ull << 20));            // 8 MB -> peak 40 MB
  float* Pg1  = (float*)(ws + (12ull << 20));            // 6 x 4 MB = [12,36)
  float* Pg2  = (float*)(ws + (36ull << 20));            // 2 x 2 MB = [36,40)
  float* Pg3  = (float*)(ws + (36ull << 20));            // 1 x 2 MB (reused after G2)

  dim3 blk(256);
  // feature extractor — SCORE-PATH bits FROZEN; K-split panels for CU coverage
  gemm_panel_k<<<dim3(8, 32, 6), blk, 0, stream>>>(x,  W1, Pg1, 2048, 512, 2048);
  combine_k<6, 1><<<dim3(4096), blk, 0, stream>>>(Pg1, b1, f1, 512, (u64)2048 * 512);
  gemm_panel_k<<<dim3(4, 32, 2), blk, 0, stream>>>(f1, W2, Pg2, 2048, 256, 512);
  combine_k<2, 1><<<dim3(2048), blk, 0, stream>>>(Pg2, b2, f2, 256, (u64)2048 * 256);
  gemm_panel_k<<<dim3(4, 32, 1), blk, 0, stream>>>(f2, W3, Pg3, 2048, 256, 256);
  combine_k<1, 0><<<dim3(2048), blk, 0, stream>>>(Pg3, b3, f,  256, (u64)2048 * 256);
  hipMemsetAsync(hist, 0, 0x100000 + 36864, stream);  // hist+hist2+Tbin+cnt+pk (contig)
  // frozen score path (2-thread/row split + 32-wide preload, bit-exact)
  fsum_seq_k <<<dim3(4),   dim3(64),   0, stream>>>(f, fsum);
  leaf_k     <<<dim3(16),  blk,        0, stream>>>(f, lf);
  tree_k     <<<dim3(1),   dim3(1024), 0, stream>>>(lf, fsq);
  score_row_k<<<dim3(782), blk,        0, stream>>>(mem, fsum, fsq, keys, hist, hist2);
  find_T_k   <<<dim3(1),   dim3(1024), 0, stream>>>(hist, hist2, Tbin);
  compact_k  <<<dim3(391), blk,        0, stream>>>(keys, Tbin, pk, cnt);
  sort_k     <<<dim3(1),   dim3(1024), 0, stream>>>(pk, idxo);
  // concat (bf16) + weight transpose-convert
  build_h_k<<<dim3(2048), blk, 0, stream>>>(f, mem, idxo, h);
  convT_k<<<dim3(64, 16), dim3(32, 8), 0, stream>>>(Wt1, W1T, 512,  2048);
  convT_k<<<dim3(64, 64), dim3(32, 8), 0, stream>>>(Wt2, W2T, 2048, 2048);
  convT_k<<<dim3(32, 64), dim3(32, 8), 0, stream>>>(Wo,  WoT, 2048, 1024);
  // task column — bf16 MFMA
  gemm_bf16_k<1, 1><<<dim3(16, 16), blk, 0, stream>>>(h,  W1T, bt1, T1, 2048, 2048, 512);
  gemm_bf16_k<1, 1><<<dim3(16, 16), blk, 0, stream>>>(T1, W2T, bt2, T2, 2048, 2048, 2048);
  gemm_bf16_k<0, 0><<<dim3(8, 16),  blk, 0, stream>>>(T2, WoT, bo, (float*)d_out, 2048, 1024, 2048);
}

// Round 18
// 455.088 us; speedup vs baseline: 1.0592x; 1.0010x over previous
//
#include <hip/hip_runtime.h>

typedef unsigned int u32;
typedef unsigned long long u64;
typedef unsigned short u16;

typedef __attribute__((ext_vector_type(8))) short bf16x8;
typedef __attribute__((ext_vector_type(4))) float f32x4;

#define FEAT 256
#define MEMN 100000

// Prevent fp contraction (hipcc defaults -ffp-contract=fast).
#define OPAQ(x) asm volatile("" : "+v"(x))

static __device__ __forceinline__ u16 f2bf(float x){   // round-to-nearest-even
  u32 u = __float_as_uint(x);
  u32 r = u + 0x7fffu + ((u >> 16) & 1u);
  return (u16)(r >> 16);
}

// ---------------- f32 GEMM panel kernel, OpenBLAS-replica bits (r16, kept) -------------
__global__ __launch_bounds__(256) void gemm_panel_k(const float* __restrict__ A,
                                                    const float* __restrict__ Bm,
                                                    float* __restrict__ Ppart,
                                                    int M, int N, int K){
  __shared__ float At[2][32][68];   // [buf][k][row]
  __shared__ float Bs[2][32][68];   // [buf][k][col]
  const int t = threadIdx.x;
  const int tx = t & 15, ty = t >> 4;
  const int bm = blockIdx.y << 6, bn = blockIdx.x << 6;
  const int p  = blockIdx.z;
  const int k0 = p * 384;
  const int k1 = (k0 + 384 < K) ? (k0 + 384) : K;
  float* Pout = Ppart + (u64)p * M * N;
  float acc[4][4];
  #pragma unroll
  for (int i = 0; i < 4; i++)
    #pragma unroll
    for (int j = 0; j < 4; j++) acc[i][j] = 0.f;

  float pa[8], pb[8];
  #pragma unroll
  for (int i = 0; i < 8; i++){
    int o = t + (i << 8);
    pa[i] = A [(u64)(bm + (o >> 5)) * K + k0 + (o & 31)];
    pb[i] = Bm[(u64)(k0 + (o >> 6)) * N + bn + (o & 63)];
  }
  #pragma unroll
  for (int i = 0; i < 8; i++){
    int o = t + (i << 8);
    At[0][o & 31][o >> 5] = pa[i];
    Bs[0][o >> 6][o & 63] = pb[i];
  }
  __syncthreads();

  int cur = 0;
  for (int kt = k0; kt < k1; kt += 32){
    const int nxt = kt + 32;
    if (nxt < k1){
      #pragma unroll
      for (int i = 0; i < 8; i++){
        int o = t + (i << 8);
        pa[i] = A [(u64)(bm + (o >> 5)) * K + nxt + (o & 31)];
        pb[i] = Bm[(u64)(nxt + (o >> 6)) * N + bn + (o & 63)];
      }
    }
    #pragma unroll
    for (int k = 0; k < 32; k++){    // ascending k: frozen chain
      float4 av = *reinterpret_cast<const float4*>(&At[cur][k][ty << 2]);
      float4 bv = *reinterpret_cast<const float4*>(&Bs[cur][k][tx << 2]);
      acc[0][0] = fmaf(av.x, bv.x, acc[0][0]); acc[0][1] = fmaf(av.x, bv.y, acc[0][1]);
      acc[0][2] = fmaf(av.x, bv.z, acc[0][2]); acc[0][3] = fmaf(av.x, bv.w, acc[0][3]);
      acc[1][0] = fmaf(av.y, bv.x, acc[1][0]); acc[1][1] = fmaf(av.y, bv.y, acc[1][1]);
      acc[1][2] = fmaf(av.y, bv.z, acc[1][2]); acc[1][3] = fmaf(av.y, bv.w, acc[1][3]);
      acc[2][0] = fmaf(av.z, bv.x, acc[2][0]); acc[2][1] = fmaf(av.z, bv.y, acc[2][1]);
      acc[2][2] = fmaf(av.z, bv.z, acc[2][2]); acc[2][3] = fmaf(av.z, bv.w, acc[2][3]);
      acc[3][0] = fmaf(av.w, bv.x, acc[3][0]); acc[3][1] = fmaf(av.w, bv.y, acc[3][1]);
      acc[3][2] = fmaf(av.w, bv.z, acc[3][2]); acc[3][3] = fmaf(av.w, bv.w, acc[3][3]);
    }
    if (nxt < k1){
      #pragma unroll
      for (int i = 0; i < 8; i++){
        int o = t + (i << 8);
        At[cur ^ 1][o & 31][o >> 5] = pa[i];
        Bs[cur ^ 1][o >> 6][o & 63] = pb[i];
      }
      __syncthreads();
      cur ^= 1;
    }
  }
  #pragma unroll
  for (int i = 0; i < 4; i++){
    int row = bm + (ty << 2) + i;
    #pragma unroll
    for (int j = 0; j < 4; j++){
      int col = bn + (tx << 2) + j;
      Pout[(u64)row * N + col] = acc[i][j];    // raw panel sum (no bias/relu)
    }
  }
}

// ---------------- combine panels left-assoc (replicates mast=0; mast+=acc_p ...) -------
template<int NP, int RELU>
__global__ __launch_bounds__(256) void combine_k(const float* __restrict__ Ppart,
                                                 const float* __restrict__ bias,
                                                 float* __restrict__ C,
                                                 int N, u64 pstride){
  u64 i = (u64)blockIdx.x * 256 + threadIdx.x;
  float v = 0.0f + Ppart[i];       // mast = 0 + p0 (exact, incl -0 corner)
  OPAQ(v);
  #pragma unroll
  for (int p = 1; p < NP; p++){ v = v + Ppart[p * pstride + i]; }
  v = v + bias[(int)(i % (u64)N)];
  if (RELU) v = v > 0.f ? v : 0.f;
  C[i] = v;
}

// ---------------- f_sum: sequential f32 over rows (frozen chains; 4 blocks) ------------
__global__ __launch_bounds__(64) void fsum_seq_k(const float* __restrict__ f,
                                                 float* __restrict__ fsum){
  int d = (blockIdx.x << 6) + threadIdx.x;
  float s = 0.f;
  for (int r = 0; r < 2048; r++) s += f[(u64)r * FEAT + d];
  fsum[d] = s;
}

// ==== numpy npyv-AVX512 pairwise base case for one 128-block of SQUARES (frozen) =======
__device__ __forceinline__ float block128_sq_avx512(const float4* base, int off, int swz){
  float e0[16], e1[16], f0[16], s16[16];
  #pragma unroll
  for (int j = 0; j < 8; j++){
    #pragma unroll
    for (int q = 0; q < 4; q++){
      float4 v = base[off + (((j << 2) + q) ^ swz)];
      float p0 = v.x * v.x, p1 = v.y * v.y, p2 = v.z * v.z, p3 = v.w * v.w;
      OPAQ(p0); OPAQ(p1); OPAQ(p2); OPAQ(p3);
      int l = q << 2;
      if (j == 0 || j == 4){ e0[l] = p0; e0[l+1] = p1; e0[l+2] = p2; e0[l+3] = p3; }
      else if (j == 1 || j == 5){ e0[l] += p0; e0[l+1] += p1; e0[l+2] += p2; e0[l+3] += p3; }
      else if (j == 2 || j == 6){ e1[l] = p0; e1[l+1] = p1; e1[l+2] = p2; e1[l+3] = p3; }
      else { e1[l] += p0; e1[l+1] += p1; e1[l+2] += p2; e1[l+3] += p3; }
    }
    if (j == 3){
      #pragma unroll
      for (int l = 0; l < 16; l++) f0[l] = e0[l] + e1[l];
    }
    if (j == 7){
      #pragma unroll
      for (int l = 0; l < 16; l++) s16[l] = f0[l] + (e0[l] + e1[l]);
    }
  }
  float h8[8], h4[4], h2[2];
  #pragma unroll
  for (int l = 0; l < 8; l++) h8[l] = s16[l] + s16[l + 8];
  #pragma unroll
  for (int l = 0; l < 4; l++) h4[l] = h8[l] + h8[l + 4];
  h2[0] = h4[0] + h4[2]; h2[1] = h4[1] + h4[3];
  return h2[0] + h2[1];
}

// ---------------- f_sq leaves + combine (frozen) ---------------------------------------
__global__ __launch_bounds__(256) void leaf_k(const float* __restrict__ f,
                                              float* __restrict__ lf){
  int b = blockIdx.x * 256 + threadIdx.x;
  lf[b] = block128_sq_avx512((const float4*)(f + (u64)b * 128), 0, 0);
}

__global__ __launch_bounds__(1024) void tree_k(const float* __restrict__ lf,
                                               float* __restrict__ fsq){
  __shared__ float sa[4096];
  __shared__ float sb[2048];
  int t = threadIdx.x;
  for (int i = t; i < 4096; i += 1024) sa[i] = lf[i];
  __syncthreads();
  float* src = sa; float* dst = sb;
  for (int len = 2048; len >= 1; len >>= 1){
    for (int i = t; i < len; i += 1024) dst[i] = src[2 * i] + src[2 * i + 1];
    __syncthreads();
    float* tmp = src; src = dst; dst = tmp;
  }
  if (t == 0) *fsq = src[0];
}

// ---------------- per-row score: 2 thr/row, 32-wide preload; 128-thr blocks ------------
// r17: grid 782 = 3.05 blocks/CU -> 33% imbalance tail (Occ 20%). 128-thr blocks,
// grid 1563 = 6.1 blocks/CU halves the tail. Arithmetic identical -> bit-frozen
// (lane pairs 2i/2i+1 stay within one wave; shfl_xor(.,1) semantics unchanged).
__global__ __launch_bounds__(128) void score_row_k(const float* __restrict__ mem,
                                                   const float* __restrict__ fsum,
                                                   const float* __restrict__ fsq_p,
                                                   u32* __restrict__ keys,
                                                   u32* __restrict__ hist,
                                                   u32* __restrict__ hist2){
  __shared__ __align__(16) float fs[256];
  __shared__ u32 lh2[256];
  const int t = threadIdx.x;
  fs[t] = fsum[t];           fs[t + 128] = fsum[t + 128];
  lh2[t] = 0;                lh2[t + 128] = 0;
  __syncthreads();
  const int sub = t & 1;
  const int row = (blockIdx.x << 6) + (t >> 1);
  float key_s = 0.f; bool live = (row < MEMN);
  if (live){
    const float4* rowp = (const float4*)(mem + (u64)row * FEAT);
    const float4* s4 = (const float4*)fs;
    float4 mvvA[16], mvvB[16];                     // all 32 loads issued before compute
    #pragma unroll
    for (int j = 0; j < 8; j++)
      #pragma unroll
      for (int cs = 0; cs < 2; cs++){
        mvvA[(j << 1) | cs] = rowp[(j << 2) + sub + (cs << 1)];
        mvvB[(j << 1) | cs] = rowp[32 + (j << 2) + sub + (cs << 1)];
      }
    float dpr[4];
    #pragma unroll
    for (int j = 0; j < 4; j++) dpr[j] = 0.f;
    float msqh[2];
    #pragma unroll
    for (int blk = 0; blk < 2; blk++){
      const int off = blk << 5;
      float e0L[8], e1L[8], f0L[8], s16L[8];
      #pragma unroll
      for (int j = 0; j < 8; j++){
        #pragma unroll
        for (int cs = 0; cs < 2; cs++){
          int kb = off + (j << 2) + sub + (cs << 1);
          float4 v = blk ? mvvB[(j << 1) | cs] : mvvA[(j << 1) | cs];
          float4 fv = s4[kb];
          float p0 = v.x * v.x, p1 = v.y * v.y, p2 = v.z * v.z, p3 = v.w * v.w;
          OPAQ(p0); OPAQ(p1); OPAQ(p2); OPAQ(p3);
          int li = cs << 2;
          if (j == 0 || j == 4){ e0L[li] = p0; e0L[li+1] = p1; e0L[li+2] = p2; e0L[li+3] = p3; }
          else if (j == 1 || j == 5){ e0L[li] += p0; e0L[li+1] += p1; e0L[li+2] += p2; e0L[li+3] += p3; }
          else if (j == 2 || j == 6){ e1L[li] = p0; e1L[li+1] = p1; e1L[li+2] = p2; e1L[li+3] = p3; }
          else { e1L[li] += p0; e1L[li+1] += p1; e1L[li+2] += p2; e1L[li+3] += p3; }
          dpr[0] = fmaf(v.x, fv.x, dpr[0]);
          dpr[1] = fmaf(v.y, fv.y, dpr[1]);
          dpr[2] = fmaf(v.z, fv.z, dpr[2]);
          dpr[3] = fmaf(v.w, fv.w, dpr[3]);
        }
        if (j == 3){
          #pragma unroll
          for (int l = 0; l < 8; l++) f0L[l] = e0L[l] + e1L[l];
        }
        if (j == 7){
          #pragma unroll
          for (int l = 0; l < 8; l++) s16L[l] = f0L[l] + (e0L[l] + e1L[l]);
        }
      }
      float h8L[4], oth[4], h4v[4];
      #pragma unroll
      for (int l = 0; l < 4; l++) h8L[l] = s16L[l] + s16L[4 + l];
      #pragma unroll
      for (int l = 0; l < 4; l++) oth[l] = __shfl_xor(h8L[l], 1);
      #pragma unroll
      for (int l = 0; l < 4; l++) h4v[l] = h8L[l] + oth[l];    // commutative: same bits
      float h2a = h4v[0] + h4v[2], h2b = h4v[1] + h4v[3];
      msqh[blk] = h2a + h2b;
    }
    float msq = msqh[0] + msqh[1];
    float od[4];
    #pragma unroll
    for (int i = 0; i < 4; i++) od[i] = __shfl_xor(dpr[i], 1);
    float b0 = dpr[0] + od[0], b1 = dpr[1] + od[1];
    float b2 = dpr[2] + od[2], b3 = dpr[3] + od[3];
    float dp = (b0 + b1) + (b2 + b3);
    float t1 = 2048.0f * msq;
    float t2 = 2.0f * dp;
    float d3 = t1 - t2;  OPAQ(d3);
    float d4 = d3 + fsq_p[0];
    key_s = -d4;
  }
  if (live && sub == 0){
    u32 bb = __float_as_uint(key_s);
    u32 key = (bb & 0x80000000u) ? ~bb : (bb | 0x80000000u);
    keys[row] = key;
    atomicAdd(&hist[key >> 14], 1u);
    atomicAdd(&lh2[key >> 24], 1u);
  }
  __syncthreads();
  u32 v0 = lh2[t];        if (v0) atomicAdd(&hist2[t], v0);
  u32 v1 = lh2[t + 128];  if (v1) atomicAdd(&hist2[t + 128], v1);
}

// ---------------- threshold fine-bin: count(bins >= T) >= 2048 -------------------------
__global__ __launch_bounds__(1024) void find_T_k(const u32* __restrict__ hist,
                                                 const u32* __restrict__ hist2,
                                                 u32* __restrict__ Tbin){
  __shared__ u32 h2[256];
  __shared__ int sh_c;
  __shared__ u32 sh_run;
  __shared__ u32 sa[1024], sb[1024];
  int t = threadIdx.x;
  if (t < 256) h2[t] = hist2[t];
  __syncthreads();
  if (t == 0){
    u32 run = 0; int cstar = 0;
    for (int c = 255; c >= 0; c--){
      u32 v = h2[c];
      if (run + v >= 2048u){ cstar = c; break; }
      run += v;
    }
    sh_c = cstar; sh_run = run;
  }
  __syncthreads();
  int cstar = sh_c; u32 run = sh_run;
  sa[t] = hist[cstar * 1024 + t];
  __syncthreads();
  u32* src = sa; u32* dst = sb;
  for (int off = 1; off < 1024; off <<= 1){
    u32 v = src[t];
    if (t + off < 1024) v += src[t + off];
    dst[t] = v;
    __syncthreads();
    u32* tmp = src; src = dst; dst = tmp;
  }
  u32 suf  = src[t];
  u32 sufn = (t < 1023) ? src[t + 1] : 0u;
  if (run + suf >= 2048u && !(run + sufn >= 2048u)) *Tbin = (u32)(cstar * 1024 + t);
}

// ---------------- compact candidates into packed (key desc, idx asc) u64 ---------------
__global__ __launch_bounds__(256) void compact_k(const u32* __restrict__ keys,
                                                 const u32* __restrict__ Tbin,
                                                 u64* __restrict__ pk,
                                                 u32* __restrict__ counter){
  int i = blockIdx.x * 256 + threadIdx.x;
  if (i >= MEMN) return;
  u32 k = keys[i];
  if ((k >> 14) >= *Tbin){
    u32 p = atomicAdd(counter, 1u);
    if (p < 4096u) pk[p] = ((u64)k << 32) | (u32)(0xFFFFFFFFu - (u32)i);
  }
}

// ---------------- one-block bitonic sort of 4096 u64 desc ------------------------------
__global__ __launch_bounds__(1024) void sort_k(const u64* __restrict__ pkin,
                                               u32* __restrict__ idxo){
  __shared__ u64 k[4096];
  for (int i = threadIdx.x; i < 4096; i += 1024) k[i] = pkin[i];
  __syncthreads();
  for (int size = 2; size <= 4096; size <<= 1){
    for (int stride = size >> 1; stride; stride >>= 1){
      #pragma unroll 2
      for (int pp = 0; pp < 2; pp++){
        int p = threadIdx.x + pp * 1024;
        int i = ((p / stride) * (stride << 1)) + (p % stride);
        int j = i + stride;
        u64 a = k[i], b = k[j];
        bool desc_ok = (a >= b);
        bool up = ((i & size) == 0);
        if (up ? !desc_ok : desc_ok){ k[i] = b; k[j] = a; }
      }
      __syncthreads();
    }
  }
  for (int i = threadIdx.x; i < 2048; i += 1024) idxo[i] = 0xFFFFFFFFu - (u32)k[i];
}

// ---------------- h = concat(f, memory[idx]) -> bf16 -----------------------------------
__global__ __launch_bounds__(256) void build_h_k(const float* __restrict__ f,
                                                 const float* __restrict__ mem,
                                                 const u32* __restrict__ idx,
                                                 u16* __restrict__ h){
  int r = blockIdx.x, t = threadIdx.x;
  h[(u64)r * 512 + t] = f2bf(f[(u64)r * FEAT + t]);
  h[(u64)r * 512 + 256 + t] = f2bf(mem[(u64)idx[r] * FEAT + t]);
}

// ---------------- transpose-convert W[K,N] f32 -> WT[N,K] bf16 -------------------------
__global__ void convT_k(const float* __restrict__ W, u16* __restrict__ WT, int K, int N){
  __shared__ float tile[32][33];
  int tx = threadIdx.x, ty = threadIdx.y;  // blockDim (32,8)
  int bk = blockIdx.y << 5, bn = blockIdx.x << 5;
  #pragma unroll
  for (int i = 0; i < 4; i++){
    int r = ty + (i << 3);
    tile[r][tx] = W[(u64)(bk + r) * N + bn + tx];
  }
  __syncthreads();
  #pragma unroll
  for (int i = 0; i < 4; i++){
    int n = ty + (i << 3);
    WT[(u64)(bn + n) * K + bk + tx] = f2bf(tile[tx][n]);
  }
}

// ---------------- bf16 MFMA GEMM (m97 template): C = act(A @ BT^T + bias) --------------
static __device__ __forceinline__ void gl_lds16(const u16* g, u16* l){
  __builtin_amdgcn_global_load_lds((const __attribute__((address_space(1))) void*)g,
                                   (__attribute__((address_space(3))) void*)l, 16, 0, 0);
}

template<int RELU, int OUTBF>
__global__ __launch_bounds__(256) void gemm_bf16_k(const u16* __restrict__ A,
                                                   const u16* __restrict__ BT,
                                                   const float* __restrict__ bias,
                                                   void* __restrict__ Cout,
                                                   int M, int N, int K){
  __shared__ u16 As[128 * 32];
  __shared__ u16 Bs[128 * 32];
  const int t = threadIdx.x;
  const int w = t >> 6, lane = t & 63;
  const int bm = blockIdx.y << 7, bn = blockIdx.x << 7;
  f32x4 acc[4][4];
  #pragma unroll
  for (int i = 0; i < 4; i++)
    #pragma unroll
    for (int j = 0; j < 4; j++) acc[i][j] = (f32x4){0.f, 0.f, 0.f, 0.f};
  const int row0 = (w >> 1) << 6, col0 = (w & 1) << 6;
  for (int kt = 0; kt < K; kt += 32){
    #pragma unroll
    for (int j = 0; j < 2; j++){
      int e = (((j << 2) + w) << 9) + (lane << 3);
      int r = e >> 5, c = e & 31;
      gl_lds16(A  + (u64)(bm + r) * K + kt + c, As + (((j << 2) + w) << 9));
      gl_lds16(BT + (u64)(bn + r) * K + kt + c, Bs + (((j << 2) + w) << 9));
    }
    __syncthreads();
    bf16x8 af[4], bfr[4];
    #pragma unroll
    for (int i = 0; i < 4; i++){
      af[i]  = *(const bf16x8*)(As + (row0 + (i << 4) + (lane & 15)) * 32 + ((lane >> 4) << 3));
      bfr[i] = *(const bf16x8*)(Bs + (col0 + (i << 4) + (lane & 15)) * 32 + ((lane >> 4) << 3));
    }
    #pragma unroll
    for (int i = 0; i < 4; i++)
      #pragma unroll
      for (int j = 0; j < 4; j++)
        acc[i][j] = __builtin_amdgcn_mfma_f32_16x16x32_bf16(af[i], bfr[j], acc[i][j], 0, 0, 0);
    __syncthreads();
  }
  #pragma unroll
  for (int i = 0; i < 4; i++){
    #pragma unroll
    for (int j = 0; j < 4; j++){
      #pragma unroll
      for (int r = 0; r < 4; r++){
        int row = bm + row0 + (i << 4) + ((lane >> 4) << 2) + r;
        int col = bn + col0 + (j << 4) + (lane & 15);
        float v = acc[i][j][r] + bias[col];
        if (RELU) v = v > 0.f ? v : 0.f;
        if (OUTBF) ((u16*)Cout)[(u64)row * N + col] = f2bf(v);
        else       ((float*)Cout)[(u64)row * N + col] = v;
      }
    }
  }
}

// ======================================================================================
extern "C" void kernel_launch(void* const* d_in, const int* in_sizes, int n_in,
                              void* d_out, int out_size, void* d_ws, size_t ws_size,
                              hipStream_t stream){
  const float* x   = (const float*)d_in[0];
  const float* W1  = (const float*)d_in[1];
  const float* b1  = (const float*)d_in[2];
  const float* W2  = (const float*)d_in[3];
  const float* b2  = (const float*)d_in[4];
  const float* W3  = (const float*)d_in[5];
  const float* b3  = (const float*)d_in[6];
  const float* mem = (const float*)d_in[7];
  const float* Wt1 = (const float*)d_in[8];
  const float* bt1 = (const float*)d_in[9];
  const float* Wt2 = (const float*)d_in[10];
  const float* bt2 = (const float*)d_in[11];
  const float* Wo  = (const float*)d_in[12];
  const float* bo  = (const float*)d_in[13];

  char* ws = (char*)d_ws;
  float* f1   = (float*)(ws + 0);
  u32*   keys = (u32*)  (ws + 0);                        // 400 KB (dead-f1 reuse)
  u32*   hist = (u32*)  (ws + 0x080000);                 // 1 MB @ 512KB
  u32*   hist2= (u32*)  (ws + 0x180000);                 // 1 KB @ 1.5MB
  u32*   Tbin = (u32*)  (ws + 0x180000 + 1024);
  u32*   cnt  = (u32*)  (ws + 0x180000 + 1028);
  u64*   pk   = (u64*)  (ws + 0x180000 + 4096);          // 32 KB
  u32*   idxo = (u32*)  (ws + 0x180000 + 40960);         // 8 KB
  float* fsum = (float*)(ws + 0x180000 + 49152);         // 1 KB
  float* lf   = (float*)(ws + 0x180000 + 50176);         // 16 KB
  float* fsq  = (float*)(ws + 0x180000 + 66560);         // 4 B
  float* f2   = (float*)(ws + (4ull  << 20));            // 2 MB
  float* f    = (float*)(ws + (6ull  << 20));            // 2 MB
  u16*   h    = (u16*)  (ws + (8ull  << 20));            // 2 MB
  u16*   W1T  = (u16*)  (ws + (10ull << 20));            // 2 MB
  u16*   W2T  = (u16*)  (ws + (12ull << 20));            // 8 MB
  u16*   WoT  = (u16*)  (ws + (20ull << 20));            // 4 MB
  u16*   T1   = (u16*)  (ws + (24ull << 20));            // 8 MB
  u16*   T2   = (u16*)  (ws + (32ull << 20));            // 8 MB -> peak 40 MB
  float* Pg1  = (float*)(ws + (12ull << 20));            // 6 x 4 MB = [12,36)
  float* Pg2  = (float*)(ws + (36ull << 20));            // 2 x 2 MB = [36,40)
  float* Pg3  = (float*)(ws + (36ull << 20));            // 1 x 2 MB (reused after G2)

  dim3 blk(256);
  // feature extractor — SCORE-PATH bits FROZEN; K-split panels for CU coverage
  gemm_panel_k<<<dim3(8, 32, 6), blk, 0, stream>>>(x,  W1, Pg1, 2048, 512, 2048);
  combine_k<6, 1><<<dim3(4096), blk, 0, stream>>>(Pg1, b1, f1, 512, (u64)2048 * 512);
  gemm_panel_k<<<dim3(4, 32, 2), blk, 0, stream>>>(f1, W2, Pg2, 2048, 256, 512);
  combine_k<2, 1><<<dim3(2048), blk, 0, stream>>>(Pg2, b2, f2, 256, (u64)2048 * 256);
  gemm_panel_k<<<dim3(4, 32, 1), blk, 0, stream>>>(f2, W3, Pg3, 2048, 256, 256);
  combine_k<1, 0><<<dim3(2048), blk, 0, stream>>>(Pg3, b3, f,  256, (u64)2048 * 256);
  hipMemsetAsync(hist, 0, 0x100000 + 36864, stream);  // hist+hist2+Tbin+cnt+pk (contig)
  // frozen score path (2-thread/row split + 32-wide preload; 128-thr blocks)
  fsum_seq_k <<<dim3(4),    dim3(64),   0, stream>>>(f, fsum);
  leaf_k     <<<dim3(16),   blk,        0, stream>>>(f, lf);
  tree_k     <<<dim3(1),    dim3(1024), 0, stream>>>(lf, fsq);
  score_row_k<<<dim3(1563), dim3(128),  0, stream>>>(mem, fsum, fsq, keys, hist, hist2);
  find_T_k   <<<dim3(1),    dim3(1024), 0, stream>>>(hist, hist2, Tbin);
  compact_k  <<<dim3(391),  blk,        0, stream>>>(keys, Tbin, pk, cnt);
  sort_k     <<<dim3(1),    dim3(1024), 0, stream>>>(pk, idxo);
  // concat (bf16) + weight transpose-convert
  build_h_k<<<dim3(2048), blk, 0, stream>>>(f, mem, idxo, h);
  convT_k<<<dim3(64, 16), dim3(32, 8), 0, stream>>>(Wt1, W1T, 512,  2048);
  convT_k<<<dim3(64, 64), dim3(32, 8), 0, stream>>>(Wt2, W2T, 2048, 2048);
  convT_k<<<dim3(32, 64), dim3(32, 8), 0, stream>>>(Wo,  WoT, 2048, 1024);
  // task column — bf16 MFMA
  gemm_bf16_k<1, 1><<<dim3(16, 16), blk, 0, stream>>>(h,  W1T, bt1, T1, 2048, 2048, 512);
  gemm_bf16_k<1, 1><<<dim3(16, 16), blk, 0, stream>>>(T1, W2T, bt2, T2, 2048, 2048, 2048);
  gemm_bf16_k<0, 0><<<dim3(8, 16),  blk, 0, stream>>>(T2, WoT, bo, (float*)d_out, 2048, 1024, 2048);
}